// Round 9
// baseline (2401.984 us; speedup 1.0000x reference)
//
#include <hip/hip_runtime.h>

#define DEV __device__ __forceinline__

static const int NN = 100000;
static const int EE = 1000000;
static const int ECAP = 1024;   // LDS-staged edges per block (32 nodes, avg ~320)

typedef unsigned int uv4 __attribute__((ext_vector_type(4)));
typedef int iv2 __attribute__((ext_vector_type(2)));

DEV float bf2f(unsigned int h) {
    unsigned int u = h << 16;
    float f;
    __builtin_memcpy(&f, &u, 4);
    return f;
}
DEV unsigned short f2bf(float f) {  // round-to-nearest-even
    unsigned int u;
    __builtin_memcpy(&u, &f, 4);
    u = u + 0x7FFFu + ((u >> 16) & 1u);
    return (unsigned short)(u >> 16);
}
DEV unsigned int pk2(float a, float b) {
    return (unsigned int)f2bf(a) | ((unsigned int)f2bf(b) << 16);
}
DEV void unpack8(uint4 u, float* v) {
    v[0] = bf2f(u.x & 0xffffu); v[1] = bf2f(u.x >> 16);
    v[2] = bf2f(u.y & 0xffffu); v[3] = bf2f(u.y >> 16);
    v[4] = bf2f(u.z & 0xffffu); v[5] = bf2f(u.z >> 16);
    v[6] = bf2f(u.w & 0xffffu); v[7] = bf2f(u.w >> 16);
}
DEV void store_row64(unsigned short* __restrict__ out, int r, const float* acc, bool relu) {
    uint4* o = reinterpret_cast<uint4*>(out + (size_t)r * 64);
#pragma unroll
    for (int c = 0; c < 8; c++) {
        float a[8];
#pragma unroll
        for (int i = 0; i < 8; i++) {
            float x = acc[c * 8 + i];
            a[i] = relu ? fmaxf(x, 0.0f) : x;
        }
        uint4 u;
        u.x = pk2(a[0], a[1]); u.y = pk2(a[2], a[3]);
        u.z = pk2(a[4], a[5]); u.w = pk2(a[6], a[7]);
        o[c] = u;
    }
}

// ---------------- CSR build (dual-graph via blockIdx.y) ----------------
__global__ __launch_bounds__(256) void k_count_dual(const int* __restrict__ d0, const int* __restrict__ d1,
                                                    int* __restrict__ c0, int* __restrict__ c1,
                                                    int* __restrict__ p0, int* __restrict__ p1, int e) {
    int g = blockIdx.y;
    const int* dst = g ? d1 : d0;
    int* cnt = g ? c1 : c0;
    int* pos = g ? p1 : p0;
    int i = blockIdx.x * blockDim.x + threadIdx.x;
    if (i < e) pos[i] = atomicAdd(&cnt[dst[i]], 1);
}
__global__ __launch_bounds__(256) void k_scan_partial_dual(const int* __restrict__ c0, const int* __restrict__ c1,
                                                           int* __restrict__ p0, int* __restrict__ p1,
                                                           float* __restrict__ v0, float* __restrict__ v1, int n) {
    int g = blockIdx.y;
    const int* cnt = g ? c1 : c0;
    int* partial = g ? p1 : p0;
    float* dinv = g ? v1 : v0;
    __shared__ int lds[256];
    int base = blockIdx.x * 1024;
    int t = threadIdx.x;
    int s = 0;
#pragma unroll
    for (int i = 0; i < 4; i++) {
        int idx = base + t * 4 + i;
        int c = (idx < n) ? cnt[idx] : 0;
        if (idx < n) dinv[idx] = rsqrtf((float)c + 1.0f);
        s += c;
    }
    lds[t] = s;
    __syncthreads();
    for (int off = 128; off > 0; off >>= 1) {
        if (t < off) lds[t] += lds[t + off];
        __syncthreads();
    }
    if (t == 0) partial[blockIdx.x] = lds[0];
}
__global__ __launch_bounds__(256) void k_scan_single_dual(int* __restrict__ p0, int* __restrict__ p1, int B) {
    int g = blockIdx.y;
    int* partial = g ? p1 : p0;
    __shared__ int lds[256];
    int t = threadIdx.x;
    int v = (t < B) ? partial[t] : 0;
    lds[t] = v;
    __syncthreads();
    for (int off = 1; off < 256; off <<= 1) {
        int x = (t >= off) ? lds[t - off] : 0;
        __syncthreads();
        lds[t] += x;
        __syncthreads();
    }
    if (t < B) partial[t] = lds[t] - v;  // exclusive
}
__global__ __launch_bounds__(256) void k_scan_write_dual(const int* __restrict__ c0, const int* __restrict__ c1,
                                                         const int* __restrict__ p0, const int* __restrict__ p1,
                                                         int* __restrict__ r0, int* __restrict__ r1,
                                                         int n, int total) {
    int g = blockIdx.y;
    const int* cnt = g ? c1 : c0;
    const int* partial = g ? p1 : p0;
    int* rowptr = g ? r1 : r0;
    __shared__ int lds[256];
    int base = blockIdx.x * 1024;
    int t = threadIdx.x;
    int v[4];
    int s = 0;
#pragma unroll
    for (int i = 0; i < 4; i++) {
        int idx = base + t * 4 + i;
        v[i] = (idx < n) ? cnt[idx] : 0;
        s += v[i];
    }
    lds[t] = s;
    __syncthreads();
    int mine = s;
    for (int off = 1; off < 256; off <<= 1) {
        int x = (t >= off) ? lds[t - off] : 0;
        __syncthreads();
        lds[t] += x;
        __syncthreads();
    }
    int run = lds[t] - mine + partial[blockIdx.x];
#pragma unroll
    for (int i = 0; i < 4; i++) {
        int idx = base + t * 4 + i;
        if (idx < n) rowptr[idx] = run;
        run += v[i];
    }
    if (blockIdx.x == 0 && t == 0) rowptr[n] = total;
}
// edge record: low word = src | ((dst&31)<<17); high word = coef bits
__global__ __launch_bounds__(256) void k_fill_dual(const int* __restrict__ s0, const int* __restrict__ s1,
                                                   const int* __restrict__ q0, const int* __restrict__ q1,
                                                   const float* __restrict__ v0, const float* __restrict__ v1,
                                                   const int* __restrict__ r0, const int* __restrict__ r1,
                                                   iv2* __restrict__ e0, iv2* __restrict__ e1, int e) {
    int g = blockIdx.y;
    const int* src = g ? s1 : s0;
    const int* dstv = src + e;
    const int* pos = g ? q1 : q0;
    const float* dinv = g ? v1 : v0;
    const int* rowptr = g ? r1 : r0;
    iv2* ec = g ? e1 : e0;
    int i = blockIdx.x * blockDim.x + threadIdx.x;
    if (i >= e) return;
    int s = src[i], d = dstv[i];
    int idx = rowptr[d] + pos[i];
    iv2 rec;
    rec.x = s | ((d & 31) << 17);
    rec.y = __float_as_int(dinv[s] * dinv[d]);
    __builtin_nontemporal_store(rec, ec + idx);
}

// ---------------- fused encoder MLP: relu(x@w1+b1)@w2+b2 -> bf16  (dual) ----------------
__global__ __launch_bounds__(256) void k_enc_dual(const float* __restrict__ x0, const float* __restrict__ x1,
                                                  const float* __restrict__ w1a, const float* __restrict__ w1b,
                                                  const float* __restrict__ b1a, const float* __restrict__ b1b,
                                                  const float* __restrict__ w2a, const float* __restrict__ w2b,
                                                  const float* __restrict__ b2a, const float* __restrict__ b2b,
                                                  unsigned short* __restrict__ y0, unsigned short* __restrict__ y1,
                                                  int n) {
    int g = blockIdx.y;
    const float* x = g ? x1 : x0;
    const float* w1 = g ? w1b : w1a;
    const float* b1 = g ? b1b : b1a;
    const float* w2 = g ? w2b : w2a;
    const float* b2 = g ? b2b : b2a;
    unsigned short* out = g ? y1 : y0;
    int r = blockIdx.x * blockDim.x + threadIdx.x;
    if (r >= n) return;
    float4 xv = reinterpret_cast<const float4*>(x)[r];
    float xk[4] = {xv.x, xv.y, xv.z, xv.w};
    float h2[64];
#pragma unroll
    for (int j = 0; j < 64; j++) h2[j] = b2[j];
#pragma unroll
    for (int c = 0; c < 8; c++) {  // h1 in chunks of 8
        float h[8];
#pragma unroll
        for (int i = 0; i < 8; i++) h[i] = b1[c * 8 + i];
#pragma unroll
        for (int k = 0; k < 4; k++) {
#pragma unroll
            for (int i = 0; i < 8; i++) h[i] = fmaf(xk[k], w1[k * 64 + c * 8 + i], h[i]);
        }
#pragma unroll
        for (int i = 0; i < 8; i++) h[i] = fmaxf(h[i], 0.0f);
#pragma unroll
        for (int i = 0; i < 8; i++) {
            const float* wr = w2 + (c * 8 + i) * 64;
#pragma unroll
            for (int j = 0; j < 64; j++) h2[j] = fmaf(h[i], wr[j], h2[j]);
        }
    }
    store_row64(out, r, h2, false);
}

// ---------------- fused GCN layer: y = relu( (A_hat x) W + b ) ----------------
// EDGE-PARALLEL phase 1: block's contiguous ec range staged in LDS; 32 thread-slots
// own contiguous edge chunks (perfect load balance, all gathers independent);
// accumulation via LDS f32 atomicAdd into agg. dst%32 is packed in the edge record.
DEV void add_edge(float (*agg)[68], int lnode, int fbase, uint4 u, float c) {
    float v[8];
    unpack8(u, v);
#pragma unroll
    for (int i = 0; i < 8; i++) atomicAdd(&agg[lnode][fbase + i], v[i] * c);
}
__global__ __launch_bounds__(256) void k_conv_dual(const unsigned short* __restrict__ x0,
                                                   const unsigned short* __restrict__ x1,
                                                   const long long* __restrict__ ec0, const long long* __restrict__ ec1,
                                                   const int* __restrict__ r0, const int* __restrict__ r1,
                                                   const float* __restrict__ v0, const float* __restrict__ v1,
                                                   const float* __restrict__ w0, const float* __restrict__ w1,
                                                   const float* __restrict__ b0, const float* __restrict__ b1,
                                                   unsigned short* __restrict__ y0, unsigned short* __restrict__ y1,
                                                   int nblk) {
    int bx = blockIdx.x;
    int xcd = bx & 7;
    int g = xcd >> 2;                    // 0..3 -> graph0, 4..7 -> graph1
    int lin = (bx >> 3) * 4 + (xcd & 3); // per-graph block index
    if (lin >= nblk) return;             // block-uniform exit (barriers safe)
    const unsigned short* x = g ? x1 : x0;
    const long long* ec = g ? ec1 : ec0;
    const int* rowptr = g ? r1 : r0;
    const float* dinv = g ? v1 : v0;
    const float* w = g ? w1 : w0;
    const float* b = g ? b1 : b0;
    unsigned short* y = g ? y1 : y0;

    __shared__ long long eds[ECAP];  // 8 KB staged edge records
    __shared__ float agg[32][68];    // pad 64->68: phase-2 reads conflict-free

    int t = threadIdx.x;
    int cl = t >> 3;   // local node 0..31 (also the edge-slot id)
    int ln = t & 7;    // feature-octet lane
    int node = lin * 32 + cl;
    int fbase = ln * 8;

    int nbase = lin * 32;
    int ebase = rowptr[nbase];
    int L = rowptr[nbase + 32] - ebase;
    int Ls = (L < ECAP) ? L : ECAP;
    for (int i = t; i < Ls; i += 256) {
        eds[i] = __builtin_nontemporal_load(ec + ebase + i);
    }

    // self-term init (plain stores; before the barrier)
    {
        float d = dinv[node];
        float d2 = d * d;
        uint4 su = *reinterpret_cast<const uint4*>(x + (size_t)node * 64 + fbase);
        float sv[8];
        unpack8(su, sv);
#pragma unroll
        for (int i = 0; i < 8; i++) agg[cl][fbase + i] = sv[i] * d2;
    }
    __syncthreads();

    // edge-parallel accumulation: slot cl owns eds[c0..c1)
    int c0 = (int)(((long long)cl * Ls) >> 5);
    int c1 = (int)(((long long)(cl + 1) * Ls) >> 5);
    int i = c0;
    for (; i + 4 <= c1; i += 4) {
        long long p0 = eds[i + 0];
        long long p1 = eds[i + 1];
        long long p2 = eds[i + 2];
        long long p3 = eds[i + 3];
        uint4 u0 = *reinterpret_cast<const uint4*>(x + (size_t)((int)p0 & 0x1FFFF) * 64 + fbase);
        uint4 u1 = *reinterpret_cast<const uint4*>(x + (size_t)((int)p1 & 0x1FFFF) * 64 + fbase);
        uint4 u2 = *reinterpret_cast<const uint4*>(x + (size_t)((int)p2 & 0x1FFFF) * 64 + fbase);
        uint4 u3 = *reinterpret_cast<const uint4*>(x + (size_t)((int)p3 & 0x1FFFF) * 64 + fbase);
        add_edge(agg, ((int)p0 >> 17) & 31, fbase, u0, __int_as_float((int)(p0 >> 32)));
        add_edge(agg, ((int)p1 >> 17) & 31, fbase, u1, __int_as_float((int)(p1 >> 32)));
        add_edge(agg, ((int)p2 >> 17) & 31, fbase, u2, __int_as_float((int)(p2 >> 32)));
        add_edge(agg, ((int)p3 >> 17) & 31, fbase, u3, __int_as_float((int)(p3 >> 32)));
    }
    if (i + 2 <= c1) {
        long long p0 = eds[i + 0];
        long long p1 = eds[i + 1];
        uint4 u0 = *reinterpret_cast<const uint4*>(x + (size_t)((int)p0 & 0x1FFFF) * 64 + fbase);
        uint4 u1 = *reinterpret_cast<const uint4*>(x + (size_t)((int)p1 & 0x1FFFF) * 64 + fbase);
        add_edge(agg, ((int)p0 >> 17) & 31, fbase, u0, __int_as_float((int)(p0 >> 32)));
        add_edge(agg, ((int)p1 >> 17) & 31, fbase, u1, __int_as_float((int)(p1 >> 32)));
        i += 2;
    }
    if (i < c1) {
        long long p0 = eds[i];
        uint4 u0 = *reinterpret_cast<const uint4*>(x + (size_t)((int)p0 & 0x1FFFF) * 64 + fbase);
        add_edge(agg, ((int)p0 >> 17) & 31, fbase, u0, __int_as_float((int)(p0 >> 32)));
    }
    // overflow fallback (essentially never): node-parallel over unstaged tail
    if (L > ECAP) {
        int gs = rowptr[node] - ebase;
        int ge = rowptr[node + 1] - ebase;
        for (int j = (gs > ECAP ? gs : ECAP); j < ge; j++) {
            long long p = __builtin_nontemporal_load(ec + ebase + j);
            uint4 u = *reinterpret_cast<const uint4*>(x + (size_t)((int)p & 0x1FFFF) * 64 + fbase);
            add_edge(agg, cl, fbase, u, __int_as_float((int)(p >> 32)));
        }
    }
    __syncthreads();

    // phase 2: out[fbase..fbase+8) = b + sum_k agg[cl][k] * W[k][fbase..]
    float out[8];
#pragma unroll
    for (int i2 = 0; i2 < 8; i2++) out[i2] = b[fbase + i2];
#pragma unroll 4
    for (int k4 = 0; k4 < 16; k4++) {
        float4 av = *reinterpret_cast<const float4*>(&agg[cl][k4 * 4]);
        float a[4] = {av.x, av.y, av.z, av.w};
#pragma unroll
        for (int kk = 0; kk < 4; kk++) {
            const float4* wr = reinterpret_cast<const float4*>(w + (k4 * 4 + kk) * 64 + fbase);
            float4 wv0 = wr[0], wv1 = wr[1];
            out[0] = fmaf(a[kk], wv0.x, out[0]);
            out[1] = fmaf(a[kk], wv0.y, out[1]);
            out[2] = fmaf(a[kk], wv0.z, out[2]);
            out[3] = fmaf(a[kk], wv0.w, out[3]);
            out[4] = fmaf(a[kk], wv1.x, out[4]);
            out[5] = fmaf(a[kk], wv1.y, out[5]);
            out[6] = fmaf(a[kk], wv1.z, out[6]);
            out[7] = fmaf(a[kk], wv1.w, out[7]);
        }
    }
    uint4 ou;
    float r[8];
#pragma unroll
    for (int i2 = 0; i2 < 8; i2++) r[i2] = fmaxf(out[i2], 0.0f);
    ou.x = pk2(r[0], r[1]); ou.y = pk2(r[2], r[3]); ou.z = pk2(r[4], r[5]); ou.w = pk2(r[6], r[7]);
    *reinterpret_cast<uint4*>(y + (size_t)node * 64 + fbase) = ou;
}

// ---------------- fused tail: concat-MLP + both heads ----------------
__global__ __launch_bounds__(256) void k_tail(const unsigned short* __restrict__ F,
                                              const unsigned short* __restrict__ S,
                                              const float* __restrict__ w1, const float* __restrict__ b1,
                                              const float* __restrict__ w2, const float* __restrict__ b2,
                                              const float* __restrict__ ow, const float* __restrict__ ob,
                                              const float* __restrict__ cw, const float* __restrict__ cb,
                                              float* __restrict__ out, int n) {
    int r = blockIdx.x * blockDim.x + threadIdx.x;
    if (r >= n) return;
    float h1[64];
#pragma unroll
    for (int j = 0; j < 64; j++) h1[j] = b1[j];
    const uint4* Fr = reinterpret_cast<const uint4*>(F + (size_t)r * 64);
    const uint4* Sr = reinterpret_cast<const uint4*>(S + (size_t)r * 64);
#pragma unroll 1
    for (int k0 = 0; k0 < 8; k0++) {
        uint4 u = Fr[k0];
        float v[8];
        unpack8(u, v);
        const float* wk = w1 + k0 * 8 * 64;
#pragma unroll
        for (int i = 0; i < 8; i++) {
#pragma unroll
            for (int j = 0; j < 64; j++) h1[j] = fmaf(v[i], wk[i * 64 + j], h1[j]);
        }
    }
#pragma unroll 1
    for (int k0 = 0; k0 < 8; k0++) {
        uint4 u = Sr[k0];
        float v[8];
        unpack8(u, v);
        const float* wk = w1 + (64 + k0 * 8) * 64;
#pragma unroll
        for (int i = 0; i < 8; i++) {
#pragma unroll
            for (int j = 0; j < 64; j++) h1[j] = fmaf(v[i], wk[i * 64 + j], h1[j]);
        }
    }
#pragma unroll
    for (int j = 0; j < 64; j++) h1[j] = fmaxf(h1[j], 0.0f);

    float nf[32];
#pragma unroll
    for (int j = 0; j < 32; j++) nf[j] = ob[j];
    float nt0 = cb[0], nt1 = cb[1];
#pragma unroll 1
    for (int c = 0; c < 8; c++) {  // h2 in chunks of 8
        float h2[8];
#pragma unroll
        for (int i = 0; i < 8; i++) h2[i] = b2[c * 8 + i];
#pragma unroll
        for (int k = 0; k < 64; k++) {
            const float* wr = w2 + k * 64 + c * 8;
#pragma unroll
            for (int i = 0; i < 8; i++) h2[i] = fmaf(h1[k], wr[i], h2[i]);
        }
#pragma unroll
        for (int i = 0; i < 8; i++) {
            int kk = c * 8 + i;
#pragma unroll
            for (int j = 0; j < 32; j++) nf[j] = fmaf(h2[i], ow[kk * 32 + j], nf[j]);
            nt0 = fmaf(h2[i], cw[kk * 2 + 0], nt0);
            nt1 = fmaf(h2[i], cw[kk * 2 + 1], nt1);
        }
    }
    float4* o = reinterpret_cast<float4*>(out + (size_t)r * 32);
#pragma unroll
    for (int c = 0; c < 8; c++) {
        o[c] = make_float4(nf[c * 4 + 0], nf[c * 4 + 1], nf[c * 4 + 2], nf[c * 4 + 3]);
    }
    float2* o2 = reinterpret_cast<float2*>(out + (size_t)NN * 32);
    o2[r] = make_float2(nt0, nt1);
}

extern "C" void kernel_launch(void* const* d_in, const int* in_sizes, int n_in,
                              void* d_out, int out_size, void* d_ws, size_t ws_size,
                              hipStream_t stream) {
    const int N = NN, E = EE;
    const float* front_x = (const float*)d_in[0];
    const float* side_x = (const float*)d_in[1];
    const int* fei = (const int*)d_in[2];
    const int* sei = (const int*)d_in[3];
    const float* fe_enc_w1 = (const float*)d_in[4];
    const float* fe_enc_b1 = (const float*)d_in[5];
    const float* fe_enc_w2 = (const float*)d_in[6];
    const float* fe_enc_b2 = (const float*)d_in[7];
    const float* fe_conv_w = (const float*)d_in[8];
    const float* fe_conv_b = (const float*)d_in[9];
    const float* se_enc_w1 = (const float*)d_in[10];
    const float* se_enc_b1 = (const float*)d_in[11];
    const float* se_enc_w2 = (const float*)d_in[12];
    const float* se_enc_b2 = (const float*)d_in[13];
    const float* se_conv_w = (const float*)d_in[14];
    const float* se_conv_b = (const float*)d_in[15];
    const float* fus_w1 = (const float*)d_in[16];
    const float* fus_b1 = (const float*)d_in[17];
    const float* fus_w2 = (const float*)d_in[18];
    const float* fus_b2 = (const float*)d_in[19];
    const float* out_w = (const float*)d_in[20];
    const float* out_b = (const float*)d_in[21];
    const float* cls_w = (const float*)d_in[22];
    const float* cls_b = (const float*)d_in[23];

    // workspace carve (256B aligned)
    char* ws = (char*)d_ws;
    size_t off = 0;
    auto take = [&](size_t bytes) -> char* {
        char* p = ws + off;
        off = (off + bytes + 255) & ~(size_t)255;
        return p;
    };
    int* zb = (int*)take((size_t)2 * N * 4);  // cnt0,cnt1 (zeroed)
    int* cnt0 = zb;
    int* cnt1 = zb + N;
    int* pos0 = (int*)take((size_t)E * 4);
    int* pos1 = (int*)take((size_t)E * 4);
    int* rp0 = (int*)take((size_t)(N + 1) * 4);
    int* rp1 = (int*)take((size_t)(N + 1) * 4);
    float* dv0 = (float*)take((size_t)N * 4);
    float* dv1 = (float*)take((size_t)N * 4);
    int* part0 = (int*)take(256 * 4);
    int* part1 = (int*)take(256 * 4);
    long long* ec0 = (long long*)take((size_t)E * 8);
    long long* ec1 = (long long*)take((size_t)E * 8);
    unsigned short* P0 = (unsigned short*)take((size_t)N * 64 * 2);
    unsigned short* P1 = (unsigned short*)take((size_t)N * 64 * 2);
    unsigned short* Q0 = (unsigned short*)take((size_t)N * 64 * 2);
    unsigned short* Q1 = (unsigned short*)take((size_t)N * 64 * 2);

    const int NB_ROW = (N + 255) / 256;
    const int NB_E = (E + 255) / 256;
    const int NB_C = N / 32;                       // 3125 blocks per graph
    const int GX_C = ((2 * NB_C + 7) / 8) * 8;     // XCD-aligned grid for conv
    const int SB = (N + 1023) / 1024;

    // ---- CSR build for both graphs ----
    hipMemsetAsync(zb, 0, (size_t)2 * N * 4, stream);
    k_count_dual<<<dim3(NB_E, 2), 256, 0, stream>>>(fei + E, sei + E, cnt0, cnt1, pos0, pos1, E);
    k_scan_partial_dual<<<dim3(SB, 2), 256, 0, stream>>>(cnt0, cnt1, part0, part1, dv0, dv1, N);
    k_scan_single_dual<<<dim3(1, 2), 256, 0, stream>>>(part0, part1, SB);
    k_scan_write_dual<<<dim3(SB, 2), 256, 0, stream>>>(cnt0, cnt1, part0, part1, rp0, rp1, N, E);
    k_fill_dual<<<dim3(NB_E, 2), 256, 0, stream>>>(fei, sei, pos0, pos1, dv0, dv1, rp0, rp1,
                                                   (iv2*)ec0, (iv2*)ec1, E);

    // ---- encoders (dual, fused 2-layer MLP) ----
    k_enc_dual<<<dim3(NB_ROW, 2), 256, 0, stream>>>(front_x, side_x, fe_enc_w1, se_enc_w1,
                                                    fe_enc_b1, se_enc_b1, fe_enc_w2, se_enc_w2,
                                                    fe_enc_b2, se_enc_b2, Q0, Q1, N);
    // ---- 3 fused conv layers (XCD-partitioned dual, edge-parallel):  Q->P->Q->P ----
    k_conv_dual<<<GX_C, 256, 0, stream>>>(Q0, Q1, ec0, ec1, rp0, rp1, dv0, dv1,
                                          fe_conv_w + 0 * 4096, se_conv_w + 0 * 4096,
                                          fe_conv_b + 0 * 64, se_conv_b + 0 * 64, P0, P1, NB_C);
    k_conv_dual<<<GX_C, 256, 0, stream>>>(P0, P1, ec0, ec1, rp0, rp1, dv0, dv1,
                                          fe_conv_w + 1 * 4096, se_conv_w + 1 * 4096,
                                          fe_conv_b + 1 * 64, se_conv_b + 1 * 64, Q0, Q1, NB_C);
    k_conv_dual<<<GX_C, 256, 0, stream>>>(Q0, Q1, ec0, ec1, rp0, rp1, dv0, dv1,
                                          fe_conv_w + 2 * 4096, se_conv_w + 2 * 4096,
                                          fe_conv_b + 2 * 64, se_conv_b + 2 * 64, P0, P1, NB_C);

    // ---- fused fusion-MLP + heads ----
    k_tail<<<NB_ROW, 256, 0, stream>>>(P0, P1, fus_w1, fus_b1, fus_w2, fus_b2,
                                       out_w, out_b, cls_w, cls_b, (float*)d_out, N);
}

// Round 10
// 987.671 us; speedup vs baseline: 2.4320x; 2.4320x over previous
//
#include <hip/hip_runtime.h>

#define DEV __device__ __forceinline__

static const int NN = 100000;
static const int EE = 1000000;
static const int ECAP = 2048;   // LDS-staged edges per block (32 nodes, avg ~320)

typedef unsigned int uv4 __attribute__((ext_vector_type(4)));

DEV float bf2f(unsigned int h) {
    unsigned int u = h << 16;
    float f;
    __builtin_memcpy(&f, &u, 4);
    return f;
}
DEV unsigned short f2bf(float f) {  // round-to-nearest-even
    unsigned int u;
    __builtin_memcpy(&u, &f, 4);
    u = u + 0x7FFFu + ((u >> 16) & 1u);
    return (unsigned short)(u >> 16);
}
DEV unsigned int pk2(float a, float b) {
    return (unsigned int)f2bf(a) | ((unsigned int)f2bf(b) << 16);
}
DEV void unpack8(uint4 u, float* v) {
    v[0] = bf2f(u.x & 0xffffu); v[1] = bf2f(u.x >> 16);
    v[2] = bf2f(u.y & 0xffffu); v[3] = bf2f(u.y >> 16);
    v[4] = bf2f(u.z & 0xffffu); v[5] = bf2f(u.z >> 16);
    v[6] = bf2f(u.w & 0xffffu); v[7] = bf2f(u.w >> 16);
}
DEV void store_row64(unsigned short* __restrict__ out, int r, const float* acc, bool relu) {
    uint4* o = reinterpret_cast<uint4*>(out + (size_t)r * 64);
#pragma unroll
    for (int c = 0; c < 8; c++) {
        float a[8];
#pragma unroll
        for (int i = 0; i < 8; i++) {
            float x = acc[c * 8 + i];
            a[i] = relu ? fmaxf(x, 0.0f) : x;
        }
        uint4 u;
        u.x = pk2(a[0], a[1]); u.y = pk2(a[2], a[3]);
        u.z = pk2(a[4], a[5]); u.w = pk2(a[6], a[7]);
        o[c] = u;
    }
}

// ---------------- CSR build (dual-graph via blockIdx.y) ----------------
__global__ __launch_bounds__(256) void k_count_dual(const int* __restrict__ d0, const int* __restrict__ d1,
                                                    int* __restrict__ c0, int* __restrict__ c1,
                                                    int* __restrict__ p0, int* __restrict__ p1, int e) {
    int g = blockIdx.y;
    const int* dst = g ? d1 : d0;
    int* cnt = g ? c1 : c0;
    int* pos = g ? p1 : p0;
    int i = blockIdx.x * blockDim.x + threadIdx.x;
    if (i < e) pos[i] = atomicAdd(&cnt[dst[i]], 1);
}
__global__ __launch_bounds__(256) void k_scan_partial_dual(const int* __restrict__ c0, const int* __restrict__ c1,
                                                           int* __restrict__ p0, int* __restrict__ p1,
                                                           float* __restrict__ v0, float* __restrict__ v1, int n) {
    int g = blockIdx.y;
    const int* cnt = g ? c1 : c0;
    int* partial = g ? p1 : p0;
    float* dinv = g ? v1 : v0;
    __shared__ int lds[256];
    int base = blockIdx.x * 1024;
    int t = threadIdx.x;
    int s = 0;
#pragma unroll
    for (int i = 0; i < 4; i++) {
        int idx = base + t * 4 + i;
        int c = (idx < n) ? cnt[idx] : 0;
        if (idx < n) dinv[idx] = rsqrtf((float)c + 1.0f);
        s += c;
    }
    lds[t] = s;
    __syncthreads();
    for (int off = 128; off > 0; off >>= 1) {
        if (t < off) lds[t] += lds[t + off];
        __syncthreads();
    }
    if (t == 0) partial[blockIdx.x] = lds[0];
}
__global__ __launch_bounds__(256) void k_scan_single_dual(int* __restrict__ p0, int* __restrict__ p1, int B) {
    int g = blockIdx.y;
    int* partial = g ? p1 : p0;
    __shared__ int lds[256];
    int t = threadIdx.x;
    int v = (t < B) ? partial[t] : 0;
    lds[t] = v;
    __syncthreads();
    for (int off = 1; off < 256; off <<= 1) {
        int x = (t >= off) ? lds[t - off] : 0;
        __syncthreads();
        lds[t] += x;
        __syncthreads();
    }
    if (t < B) partial[t] = lds[t] - v;  // exclusive
}
__global__ __launch_bounds__(256) void k_scan_write_dual(const int* __restrict__ c0, const int* __restrict__ c1,
                                                         const int* __restrict__ p0, const int* __restrict__ p1,
                                                         int* __restrict__ r0, int* __restrict__ r1,
                                                         int n, int total) {
    int g = blockIdx.y;
    const int* cnt = g ? c1 : c0;
    const int* partial = g ? p1 : p0;
    int* rowptr = g ? r1 : r0;
    __shared__ int lds[256];
    int base = blockIdx.x * 1024;
    int t = threadIdx.x;
    int v[4];
    int s = 0;
#pragma unroll
    for (int i = 0; i < 4; i++) {
        int idx = base + t * 4 + i;
        v[i] = (idx < n) ? cnt[idx] : 0;
        s += v[i];
    }
    lds[t] = s;
    __syncthreads();
    int mine = s;
    for (int off = 1; off < 256; off <<= 1) {
        int x = (t >= off) ? lds[t - off] : 0;
        __syncthreads();
        lds[t] += x;
        __syncthreads();
    }
    int run = lds[t] - mine + partial[blockIdx.x];
#pragma unroll
    for (int i = 0; i < 4; i++) {
        int idx = base + t * 4 + i;
        if (idx < n) rowptr[idx] = run;
        run += v[i];
    }
    if (blockIdx.x == 0 && t == 0) rowptr[n] = total;
}
// fill: col[idx] = src only (coef is algebraically eliminated via pre-scaled features)
__global__ __launch_bounds__(256) void k_fill_dual(const int* __restrict__ s0, const int* __restrict__ s1,
                                                   const int* __restrict__ q0, const int* __restrict__ q1,
                                                   const int* __restrict__ r0, const int* __restrict__ r1,
                                                   int* __restrict__ col0, int* __restrict__ col1, int e) {
    int g = blockIdx.y;
    const int* src = g ? s1 : s0;
    const int* dstv = src + e;
    const int* pos = g ? q1 : q0;
    const int* rowptr = g ? r1 : r0;
    int* col = g ? col1 : col0;
    int i = blockIdx.x * blockDim.x + threadIdx.x;
    if (i >= e) return;
    int s = src[i], d = dstv[i];
    int idx = rowptr[d] + pos[i];
    __builtin_nontemporal_store(s, col + idx);
}

// ---------------- fused encoder MLP: (relu(x@w1+b1)@w2+b2) * dinv -> bf16  (dual) ----------------
__global__ __launch_bounds__(256) void k_enc_dual(const float* __restrict__ x0, const float* __restrict__ x1,
                                                  const float* __restrict__ w1a, const float* __restrict__ w1b,
                                                  const float* __restrict__ b1a, const float* __restrict__ b1b,
                                                  const float* __restrict__ w2a, const float* __restrict__ w2b,
                                                  const float* __restrict__ b2a, const float* __restrict__ b2b,
                                                  const float* __restrict__ v0, const float* __restrict__ v1,
                                                  unsigned short* __restrict__ y0, unsigned short* __restrict__ y1,
                                                  int n) {
    int g = blockIdx.y;
    const float* x = g ? x1 : x0;
    const float* w1 = g ? w1b : w1a;
    const float* b1 = g ? b1b : b1a;
    const float* w2 = g ? w2b : w2a;
    const float* b2 = g ? b2b : b2a;
    const float* dinv = g ? v1 : v0;
    unsigned short* out = g ? y1 : y0;
    int r = blockIdx.x * blockDim.x + threadIdx.x;
    if (r >= n) return;
    float4 xv = reinterpret_cast<const float4*>(x)[r];
    float xk[4] = {xv.x, xv.y, xv.z, xv.w};
    float h2[64];
#pragma unroll
    for (int j = 0; j < 64; j++) h2[j] = b2[j];
#pragma unroll
    for (int c = 0; c < 8; c++) {  // h1 in chunks of 8
        float h[8];
#pragma unroll
        for (int i = 0; i < 8; i++) h[i] = b1[c * 8 + i];
#pragma unroll
        for (int k = 0; k < 4; k++) {
#pragma unroll
            for (int i = 0; i < 8; i++) h[i] = fmaf(xk[k], w1[k * 64 + c * 8 + i], h[i]);
        }
#pragma unroll
        for (int i = 0; i < 8; i++) h[i] = fmaxf(h[i], 0.0f);
#pragma unroll
        for (int i = 0; i < 8; i++) {
            const float* wr = w2 + (c * 8 + i) * 64;
#pragma unroll
            for (int j = 0; j < 64; j++) h2[j] = fmaf(h[i], wr[j], h2[j]);
        }
    }
    float d = dinv[r];
#pragma unroll
    for (int j = 0; j < 64; j++) h2[j] *= d;   // pre-scale for conv layer 1
    store_row64(out, r, h2, false);
}

// ---------------- fused GCN layer (pre-scaled input h' = h*dinv) ----------------
// z[d] = dinv[d] * (sum_{s in N(d)} h'[s] + h'[d]);  y = relu(z W + b);
// store y*dinv (scale_store=1, feeds next conv) or y (scale_store=0, final layer).
DEV void add_edge_v(float* acc, uint4 u) {
    float v[8];
    unpack8(u, v);
#pragma unroll
    for (int i = 0; i < 8; i++) acc[i] += v[i];
}
__global__ __launch_bounds__(256) void k_conv_dual(const unsigned short* __restrict__ x0,
                                                   const unsigned short* __restrict__ x1,
                                                   const int* __restrict__ col0, const int* __restrict__ col1,
                                                   const int* __restrict__ r0, const int* __restrict__ r1,
                                                   const float* __restrict__ v0, const float* __restrict__ v1,
                                                   const float* __restrict__ w0, const float* __restrict__ w1,
                                                   const float* __restrict__ b0, const float* __restrict__ b1,
                                                   unsigned short* __restrict__ y0, unsigned short* __restrict__ y1,
                                                   int nblk, int scale_store) {
    int bx = blockIdx.x;
    int xcd = bx & 7;
    int g = xcd >> 2;                    // 0..3 -> graph0, 4..7 -> graph1
    int lin = (bx >> 3) * 4 + (xcd & 3); // per-graph block index
    if (lin >= nblk) return;             // block-uniform exit (barriers safe)
    const unsigned short* x = g ? x1 : x0;
    const int* col = g ? col1 : col0;
    const int* rowptr = g ? r1 : r0;
    const float* dinv = g ? v1 : v0;
    const float* w = g ? w1 : w0;
    const float* b = g ? b1 : b0;
    unsigned short* y = g ? y1 : y0;

    __shared__ int eds[ECAP];        // 8 KB staged src indices
    __shared__ float agg[32][68];    // pad 64->68: phase-2 reads conflict-free

    int t = threadIdx.x;
    int cl = t >> 3;   // local node 0..31
    int ln = t & 7;    // feature-octet lane
    int node = lin * 32 + cl;
    int fbase = ln * 8;

    int nbase = lin * 32;
    int ebase = rowptr[nbase];
    int L = rowptr[nbase + 32] - ebase;
    int Ls = (L < ECAP) ? L : ECAP;
    for (int i = t; i < Ls; i += 256) {
        eds[i] = __builtin_nontemporal_load(col + ebase + i);
    }

    float acc[8];
    float d = dinv[node];
    {
        uint4 su = *reinterpret_cast<const uint4*>(x + (size_t)node * 64 + fbase);
        float sv[8];
        unpack8(su, sv);
#pragma unroll
        for (int i = 0; i < 8; i++) acc[i] = sv[i];   // self term h'[d]
    }
    int e = rowptr[node] - ebase, e1 = rowptr[node + 1] - ebase;
    __syncthreads();

    if (e1 <= ECAP) {
        // 8 independent gathers per epoch (deg~10 -> ~2 epochs)
        for (; e + 8 <= e1; e += 8) {
            int s0 = eds[e + 0], s1 = eds[e + 1], s2 = eds[e + 2], s3 = eds[e + 3];
            int s4 = eds[e + 4], s5 = eds[e + 5], s6 = eds[e + 6], s7 = eds[e + 7];
            uint4 u0 = *reinterpret_cast<const uint4*>(x + (size_t)s0 * 64 + fbase);
            uint4 u1 = *reinterpret_cast<const uint4*>(x + (size_t)s1 * 64 + fbase);
            uint4 u2 = *reinterpret_cast<const uint4*>(x + (size_t)s2 * 64 + fbase);
            uint4 u3 = *reinterpret_cast<const uint4*>(x + (size_t)s3 * 64 + fbase);
            uint4 u4 = *reinterpret_cast<const uint4*>(x + (size_t)s4 * 64 + fbase);
            uint4 u5 = *reinterpret_cast<const uint4*>(x + (size_t)s5 * 64 + fbase);
            uint4 u6 = *reinterpret_cast<const uint4*>(x + (size_t)s6 * 64 + fbase);
            uint4 u7 = *reinterpret_cast<const uint4*>(x + (size_t)s7 * 64 + fbase);
            add_edge_v(acc, u0); add_edge_v(acc, u1); add_edge_v(acc, u2); add_edge_v(acc, u3);
            add_edge_v(acc, u4); add_edge_v(acc, u5); add_edge_v(acc, u6); add_edge_v(acc, u7);
        }
        if (e + 4 <= e1) {
            int s0 = eds[e + 0], s1 = eds[e + 1], s2 = eds[e + 2], s3 = eds[e + 3];
            uint4 u0 = *reinterpret_cast<const uint4*>(x + (size_t)s0 * 64 + fbase);
            uint4 u1 = *reinterpret_cast<const uint4*>(x + (size_t)s1 * 64 + fbase);
            uint4 u2 = *reinterpret_cast<const uint4*>(x + (size_t)s2 * 64 + fbase);
            uint4 u3 = *reinterpret_cast<const uint4*>(x + (size_t)s3 * 64 + fbase);
            add_edge_v(acc, u0); add_edge_v(acc, u1); add_edge_v(acc, u2); add_edge_v(acc, u3);
            e += 4;
        }
        if (e + 2 <= e1) {
            int s0 = eds[e + 0], s1 = eds[e + 1];
            uint4 u0 = *reinterpret_cast<const uint4*>(x + (size_t)s0 * 64 + fbase);
            uint4 u1 = *reinterpret_cast<const uint4*>(x + (size_t)s1 * 64 + fbase);
            add_edge_v(acc, u0); add_edge_v(acc, u1);
            e += 2;
        }
        if (e < e1) {
            int s0 = eds[e];
            uint4 u0 = *reinterpret_cast<const uint4*>(x + (size_t)s0 * 64 + fbase);
            add_edge_v(acc, u0);
        }
    } else {
        // overflow fallback (essentially never)
        for (; e < e1; e++) {
            int s0 = __builtin_nontemporal_load(col + ebase + e);
            uint4 u0 = *reinterpret_cast<const uint4*>(x + (size_t)s0 * 64 + fbase);
            add_edge_v(acc, u0);
        }
    }
    // z = dinv[d] * acc
#pragma unroll
    for (int i = 0; i < 8; i += 4) {
        *reinterpret_cast<float4*>(&agg[cl][fbase + i]) =
            make_float4(acc[i] * d, acc[i + 1] * d, acc[i + 2] * d, acc[i + 3] * d);
    }
    __syncthreads();

    // phase 2: out[fbase..fbase+8) = b + sum_k agg[cl][k] * W[k][fbase..]
    float out[8];
#pragma unroll
    for (int i = 0; i < 8; i++) out[i] = b[fbase + i];
#pragma unroll 4
    for (int k4 = 0; k4 < 16; k4++) {
        float4 av = *reinterpret_cast<const float4*>(&agg[cl][k4 * 4]);
        float a[4] = {av.x, av.y, av.z, av.w};
#pragma unroll
        for (int kk = 0; kk < 4; kk++) {
            const float4* wr = reinterpret_cast<const float4*>(w + (k4 * 4 + kk) * 64 + fbase);
            float4 wv0 = wr[0], wv1 = wr[1];
            out[0] = fmaf(a[kk], wv0.x, out[0]);
            out[1] = fmaf(a[kk], wv0.y, out[1]);
            out[2] = fmaf(a[kk], wv0.z, out[2]);
            out[3] = fmaf(a[kk], wv0.w, out[3]);
            out[4] = fmaf(a[kk], wv1.x, out[4]);
            out[5] = fmaf(a[kk], wv1.y, out[5]);
            out[6] = fmaf(a[kk], wv1.z, out[6]);
            out[7] = fmaf(a[kk], wv1.w, out[7]);
        }
    }
    float sc = scale_store ? d : 1.0f;
    uint4 ou;
    float r[8];
#pragma unroll
    for (int i = 0; i < 8; i++) r[i] = fmaxf(out[i], 0.0f) * sc;
    ou.x = pk2(r[0], r[1]); ou.y = pk2(r[2], r[3]); ou.z = pk2(r[4], r[5]); ou.w = pk2(r[6], r[7]);
    *reinterpret_cast<uint4*>(y + (size_t)node * 64 + fbase) = ou;
}

// ---------------- fused tail: concat-MLP + both heads ----------------
__global__ __launch_bounds__(256) void k_tail(const unsigned short* __restrict__ F,
                                              const unsigned short* __restrict__ S,
                                              const float* __restrict__ w1, const float* __restrict__ b1,
                                              const float* __restrict__ w2, const float* __restrict__ b2,
                                              const float* __restrict__ ow, const float* __restrict__ ob,
                                              const float* __restrict__ cw, const float* __restrict__ cb,
                                              float* __restrict__ out, int n) {
    int r = blockIdx.x * blockDim.x + threadIdx.x;
    if (r >= n) return;
    float h1[64];
#pragma unroll
    for (int j = 0; j < 64; j++) h1[j] = b1[j];
    const uint4* Fr = reinterpret_cast<const uint4*>(F + (size_t)r * 64);
    const uint4* Sr = reinterpret_cast<const uint4*>(S + (size_t)r * 64);
#pragma unroll 1
    for (int k0 = 0; k0 < 8; k0++) {
        uint4 u = Fr[k0];
        float v[8];
        unpack8(u, v);
        const float* wk = w1 + k0 * 8 * 64;
#pragma unroll
        for (int i = 0; i < 8; i++) {
#pragma unroll
            for (int j = 0; j < 64; j++) h1[j] = fmaf(v[i], wk[i * 64 + j], h1[j]);
        }
    }
#pragma unroll 1
    for (int k0 = 0; k0 < 8; k0++) {
        uint4 u = Sr[k0];
        float v[8];
        unpack8(u, v);
        const float* wk = w1 + (64 + k0 * 8) * 64;
#pragma unroll
        for (int i = 0; i < 8; i++) {
#pragma unroll
            for (int j = 0; j < 64; j++) h1[j] = fmaf(v[i], wk[i * 64 + j], h1[j]);
        }
    }
#pragma unroll
    for (int j = 0; j < 64; j++) h1[j] = fmaxf(h1[j], 0.0f);

    float nf[32];
#pragma unroll
    for (int j = 0; j < 32; j++) nf[j] = ob[j];
    float nt0 = cb[0], nt1 = cb[1];
#pragma unroll 1
    for (int c = 0; c < 8; c++) {  // h2 in chunks of 8
        float h2[8];
#pragma unroll
        for (int i = 0; i < 8; i++) h2[i] = b2[c * 8 + i];
#pragma unroll
        for (int k = 0; k < 64; k++) {
            const float* wr = w2 + k * 64 + c * 8;
#pragma unroll
            for (int i = 0; i < 8; i++) h2[i] = fmaf(h1[k], wr[i], h2[i]);
        }
#pragma unroll
        for (int i = 0; i < 8; i++) {
            int kk = c * 8 + i;
#pragma unroll
            for (int j = 0; j < 32; j++) nf[j] = fmaf(h2[i], ow[kk * 32 + j], nf[j]);
            nt0 = fmaf(h2[i], cw[kk * 2 + 0], nt0);
            nt1 = fmaf(h2[i], cw[kk * 2 + 1], nt1);
        }
    }
    float4* o = reinterpret_cast<float4*>(out + (size_t)r * 32);
#pragma unroll
    for (int c = 0; c < 8; c++) {
        o[c] = make_float4(nf[c * 4 + 0], nf[c * 4 + 1], nf[c * 4 + 2], nf[c * 4 + 3]);
    }
    float2* o2 = reinterpret_cast<float2*>(out + (size_t)NN * 32);
    o2[r] = make_float2(nt0, nt1);
}

extern "C" void kernel_launch(void* const* d_in, const int* in_sizes, int n_in,
                              void* d_out, int out_size, void* d_ws, size_t ws_size,
                              hipStream_t stream) {
    const int N = NN, E = EE;
    const float* front_x = (const float*)d_in[0];
    const float* side_x = (const float*)d_in[1];
    const int* fei = (const int*)d_in[2];
    const int* sei = (const int*)d_in[3];
    const float* fe_enc_w1 = (const float*)d_in[4];
    const float* fe_enc_b1 = (const float*)d_in[5];
    const float* fe_enc_w2 = (const float*)d_in[6];
    const float* fe_enc_b2 = (const float*)d_in[7];
    const float* fe_conv_w = (const float*)d_in[8];
    const float* fe_conv_b = (const float*)d_in[9];
    const float* se_enc_w1 = (const float*)d_in[10];
    const float* se_enc_b1 = (const float*)d_in[11];
    const float* se_enc_w2 = (const float*)d_in[12];
    const float* se_enc_b2 = (const float*)d_in[13];
    const float* se_conv_w = (const float*)d_in[14];
    const float* se_conv_b = (const float*)d_in[15];
    const float* fus_w1 = (const float*)d_in[16];
    const float* fus_b1 = (const float*)d_in[17];
    const float* fus_w2 = (const float*)d_in[18];
    const float* fus_b2 = (const float*)d_in[19];
    const float* out_w = (const float*)d_in[20];
    const float* out_b = (const float*)d_in[21];
    const float* cls_w = (const float*)d_in[22];
    const float* cls_b = (const float*)d_in[23];

    // workspace carve (256B aligned)
    char* ws = (char*)d_ws;
    size_t off = 0;
    auto take = [&](size_t bytes) -> char* {
        char* p = ws + off;
        off = (off + bytes + 255) & ~(size_t)255;
        return p;
    };
    int* zb = (int*)take((size_t)2 * N * 4);  // cnt0,cnt1 (zeroed)
    int* cnt0 = zb;
    int* cnt1 = zb + N;
    int* pos0 = (int*)take((size_t)E * 4);
    int* pos1 = (int*)take((size_t)E * 4);
    int* rp0 = (int*)take((size_t)(N + 1) * 4);
    int* rp1 = (int*)take((size_t)(N + 1) * 4);
    float* dv0 = (float*)take((size_t)N * 4);
    float* dv1 = (float*)take((size_t)N * 4);
    int* part0 = (int*)take(256 * 4);
    int* part1 = (int*)take(256 * 4);
    int* col0 = (int*)take((size_t)E * 4);
    int* col1 = (int*)take((size_t)E * 4);
    unsigned short* P0 = (unsigned short*)take((size_t)N * 64 * 2);
    unsigned short* P1 = (unsigned short*)take((size_t)N * 64 * 2);
    unsigned short* Q0 = (unsigned short*)take((size_t)N * 64 * 2);
    unsigned short* Q1 = (unsigned short*)take((size_t)N * 64 * 2);

    const int NB_ROW = (N + 255) / 256;
    const int NB_E = (E + 255) / 256;
    const int NB_C = N / 32;                       // 3125 blocks per graph
    const int GX_C = ((2 * NB_C + 7) / 8) * 8;     // XCD-aligned grid for conv
    const int SB = (N + 1023) / 1024;

    // ---- CSR build for both graphs ----
    hipMemsetAsync(zb, 0, (size_t)2 * N * 4, stream);
    k_count_dual<<<dim3(NB_E, 2), 256, 0, stream>>>(fei + E, sei + E, cnt0, cnt1, pos0, pos1, E);
    k_scan_partial_dual<<<dim3(SB, 2), 256, 0, stream>>>(cnt0, cnt1, part0, part1, dv0, dv1, N);
    k_scan_single_dual<<<dim3(1, 2), 256, 0, stream>>>(part0, part1, SB);
    k_scan_write_dual<<<dim3(SB, 2), 256, 0, stream>>>(cnt0, cnt1, part0, part1, rp0, rp1, N, E);
    k_fill_dual<<<dim3(NB_E, 2), 256, 0, stream>>>(fei, sei, pos0, pos1, rp0, rp1, col0, col1, E);

    // ---- encoders (dual, fused 2-layer MLP; output pre-scaled by dinv) ----
    k_enc_dual<<<dim3(NB_ROW, 2), 256, 0, stream>>>(front_x, side_x, fe_enc_w1, se_enc_w1,
                                                    fe_enc_b1, se_enc_b1, fe_enc_w2, se_enc_w2,
                                                    fe_enc_b2, se_enc_b2, dv0, dv1, Q0, Q1, N);
    // ---- 3 fused conv layers (XCD-partitioned dual, LDS-staged col):  Q->P->Q->P ----
    k_conv_dual<<<GX_C, 256, 0, stream>>>(Q0, Q1, col0, col1, rp0, rp1, dv0, dv1,
                                          fe_conv_w + 0 * 4096, se_conv_w + 0 * 4096,
                                          fe_conv_b + 0 * 64, se_conv_b + 0 * 64, P0, P1, NB_C, 1);
    k_conv_dual<<<GX_C, 256, 0, stream>>>(P0, P1, col0, col1, rp0, rp1, dv0, dv1,
                                          fe_conv_w + 1 * 4096, se_conv_w + 1 * 4096,
                                          fe_conv_b + 1 * 64, se_conv_b + 1 * 64, Q0, Q1, NB_C, 1);
    k_conv_dual<<<GX_C, 256, 0, stream>>>(Q0, Q1, col0, col1, rp0, rp1, dv0, dv1,
                                          fe_conv_w + 2 * 4096, se_conv_w + 2 * 4096,
                                          fe_conv_b + 2 * 64, se_conv_b + 2 * 64, P0, P1, NB_C, 0);

    // ---- fused fusion-MLP + heads ----
    k_tail<<<NB_ROW, 256, 0, stream>>>(P0, P1, fus_w1, fus_b1, fus_w2, fus_b2,
                                       out_w, out_b, cls_w, cls_b, (float*)d_out, N);
}

// Round 11
// 731.508 us; speedup vs baseline: 3.2836x; 1.3502x over previous
//
#include <hip/hip_runtime.h>

#define DEV __device__ __forceinline__

static const int NN = 100000;
static const int EE = 1000000;
static const int ECAP = 2048;   // LDS-staged edges per block (32 nodes, avg ~320)

typedef unsigned int uv4 __attribute__((ext_vector_type(4)));

DEV float bf2f(unsigned int h) {
    unsigned int u = h << 16;
    float f;
    __builtin_memcpy(&f, &u, 4);
    return f;
}
DEV unsigned short f2bf(float f) {  // round-to-nearest-even
    unsigned int u;
    __builtin_memcpy(&u, &f, 4);
    u = u + 0x7FFFu + ((u >> 16) & 1u);
    return (unsigned short)(u >> 16);
}
DEV unsigned int pk2(float a, float b) {
    return (unsigned int)f2bf(a) | ((unsigned int)f2bf(b) << 16);
}
DEV void unpack8(uint4 u, float* v) {
    v[0] = bf2f(u.x & 0xffffu); v[1] = bf2f(u.x >> 16);
    v[2] = bf2f(u.y & 0xffffu); v[3] = bf2f(u.y >> 16);
    v[4] = bf2f(u.z & 0xffffu); v[5] = bf2f(u.z >> 16);
    v[6] = bf2f(u.w & 0xffffu); v[7] = bf2f(u.w >> 16);
}
DEV void store_row64(unsigned short* __restrict__ out, int r, const float* acc, bool relu) {
    uint4* o = reinterpret_cast<uint4*>(out + (size_t)r * 64);
#pragma unroll
    for (int c = 0; c < 8; c++) {
        float a[8];
#pragma unroll
        for (int i = 0; i < 8; i++) {
            float x = acc[c * 8 + i];
            a[i] = relu ? fmaxf(x, 0.0f) : x;
        }
        uint4 u;
        u.x = pk2(a[0], a[1]); u.y = pk2(a[2], a[3]);
        u.z = pk2(a[4], a[5]); u.w = pk2(a[6], a[7]);
        o[c] = u;
    }
}

// ---------------- CSR build (dual-graph via blockIdx.y) ----------------
__global__ __launch_bounds__(256) void k_count_dual(const int* __restrict__ d0, const int* __restrict__ d1,
                                                    int* __restrict__ c0, int* __restrict__ c1,
                                                    int* __restrict__ p0, int* __restrict__ p1, int e) {
    int g = blockIdx.y;
    const int* dst = g ? d1 : d0;
    int* cnt = g ? c1 : c0;
    int* pos = g ? p1 : p0;
    int i = blockIdx.x * blockDim.x + threadIdx.x;
    if (i < e) pos[i] = atomicAdd(&cnt[dst[i]], 1);
}
__global__ __launch_bounds__(256) void k_scan_partial_dual(const int* __restrict__ c0, const int* __restrict__ c1,
                                                           int* __restrict__ p0, int* __restrict__ p1,
                                                           float* __restrict__ v0, float* __restrict__ v1, int n) {
    int g = blockIdx.y;
    const int* cnt = g ? c1 : c0;
    int* partial = g ? p1 : p0;
    float* dinv = g ? v1 : v0;
    __shared__ int lds[256];
    int base = blockIdx.x * 1024;
    int t = threadIdx.x;
    int s = 0;
#pragma unroll
    for (int i = 0; i < 4; i++) {
        int idx = base + t * 4 + i;
        int c = (idx < n) ? cnt[idx] : 0;
        if (idx < n) dinv[idx] = rsqrtf((float)c + 1.0f);
        s += c;
    }
    lds[t] = s;
    __syncthreads();
    for (int off = 128; off > 0; off >>= 1) {
        if (t < off) lds[t] += lds[t + off];
        __syncthreads();
    }
    if (t == 0) partial[blockIdx.x] = lds[0];
}
__global__ __launch_bounds__(256) void k_scan_single_dual(int* __restrict__ p0, int* __restrict__ p1, int B) {
    int g = blockIdx.y;
    int* partial = g ? p1 : p0;
    __shared__ int lds[256];
    int t = threadIdx.x;
    int v = (t < B) ? partial[t] : 0;
    lds[t] = v;
    __syncthreads();
    for (int off = 1; off < 256; off <<= 1) {
        int x = (t >= off) ? lds[t - off] : 0;
        __syncthreads();
        lds[t] += x;
        __syncthreads();
    }
    if (t < B) partial[t] = lds[t] - v;  // exclusive
}
__global__ __launch_bounds__(256) void k_scan_write_dual(const int* __restrict__ c0, const int* __restrict__ c1,
                                                         const int* __restrict__ p0, const int* __restrict__ p1,
                                                         int* __restrict__ r0, int* __restrict__ r1,
                                                         int n, int total) {
    int g = blockIdx.y;
    const int* cnt = g ? c1 : c0;
    const int* partial = g ? p1 : p0;
    int* rowptr = g ? r1 : r0;
    __shared__ int lds[256];
    int base = blockIdx.x * 1024;
    int t = threadIdx.x;
    int v[4];
    int s = 0;
#pragma unroll
    for (int i = 0; i < 4; i++) {
        int idx = base + t * 4 + i;
        v[i] = (idx < n) ? cnt[idx] : 0;
        s += v[i];
    }
    lds[t] = s;
    __syncthreads();
    int mine = s;
    for (int off = 1; off < 256; off <<= 1) {
        int x = (t >= off) ? lds[t - off] : 0;
        __syncthreads();
        lds[t] += x;
        __syncthreads();
    }
    int run = lds[t] - mine + partial[blockIdx.x];
#pragma unroll
    for (int i = 0; i < 4; i++) {
        int idx = base + t * 4 + i;
        if (idx < n) rowptr[idx] = run;
        run += v[i];
    }
    if (blockIdx.x == 0 && t == 0) rowptr[n] = total;
}
// fill: col[idx] = src only (coef is algebraically eliminated via pre-scaled features)
__global__ __launch_bounds__(256) void k_fill_dual(const int* __restrict__ s0, const int* __restrict__ s1,
                                                   const int* __restrict__ q0, const int* __restrict__ q1,
                                                   const int* __restrict__ r0, const int* __restrict__ r1,
                                                   int* __restrict__ col0, int* __restrict__ col1, int e) {
    int g = blockIdx.y;
    const int* src = g ? s1 : s0;
    const int* dstv = src + e;
    const int* pos = g ? q1 : q0;
    const int* rowptr = g ? r1 : r0;
    int* col = g ? col1 : col0;
    int i = blockIdx.x * blockDim.x + threadIdx.x;
    if (i >= e) return;
    int s = src[i], d = dstv[i];
    int idx = rowptr[d] + pos[i];
    __builtin_nontemporal_store(s, col + idx);
}

// ---------------- fused encoder MLP: (relu(x@w1+b1)@w2+b2) * dinv -> bf16  (dual) ----------------
// Register-bounded: h2 computed in 4 chunks of 16 columns; h1 (8-chunks) recomputed
// per output chunk (x has only 4 features, so recompute is ~4*32 FMA/row — cheap).
__global__ __launch_bounds__(256, 4) void k_enc_dual(const float* __restrict__ x0, const float* __restrict__ x1,
                                                     const float* __restrict__ w1a, const float* __restrict__ w1b,
                                                     const float* __restrict__ b1a, const float* __restrict__ b1b,
                                                     const float* __restrict__ w2a, const float* __restrict__ w2b,
                                                     const float* __restrict__ b2a, const float* __restrict__ b2b,
                                                     const float* __restrict__ v0, const float* __restrict__ v1,
                                                     unsigned short* __restrict__ y0, unsigned short* __restrict__ y1,
                                                     int n) {
    int g = blockIdx.y;
    const float* x = g ? x1 : x0;
    const float* w1 = g ? w1b : w1a;
    const float* b1 = g ? b1b : b1a;
    const float* w2 = g ? w2b : w2a;
    const float* b2 = g ? b2b : b2a;
    const float* dinv = g ? v1 : v0;
    unsigned short* out = g ? y1 : y0;
    int r = blockIdx.x * blockDim.x + threadIdx.x;
    if (r >= n) return;
    float4 xv = reinterpret_cast<const float4*>(x)[r];
    float xk[4] = {xv.x, xv.y, xv.z, xv.w};
    float d = dinv[r];
    uint4* o = reinterpret_cast<uint4*>(out + (size_t)r * 64);
#pragma unroll 1
    for (int oc = 0; oc < 4; oc++) {          // 16 output columns per chunk
        float h2[16];
#pragma unroll
        for (int j = 0; j < 16; j++) h2[j] = b2[oc * 16 + j];
#pragma unroll 1
        for (int c = 0; c < 8; c++) {         // h1 in chunks of 8 (recomputed)
            float h[8];
#pragma unroll
            for (int i = 0; i < 8; i++) h[i] = b1[c * 8 + i];
#pragma unroll
            for (int k = 0; k < 4; k++) {
#pragma unroll
                for (int i = 0; i < 8; i++) h[i] = fmaf(xk[k], w1[k * 64 + c * 8 + i], h[i]);
            }
#pragma unroll
            for (int i = 0; i < 8; i++) h[i] = fmaxf(h[i], 0.0f);
#pragma unroll
            for (int i = 0; i < 8; i++) {
                const float* wr = w2 + (c * 8 + i) * 64 + oc * 16;
#pragma unroll
                for (int j = 0; j < 16; j++) h2[j] = fmaf(h[i], wr[j], h2[j]);
            }
        }
        uint4 u0, u1;
        u0.x = pk2(h2[0] * d, h2[1] * d);   u0.y = pk2(h2[2] * d, h2[3] * d);
        u0.z = pk2(h2[4] * d, h2[5] * d);   u0.w = pk2(h2[6] * d, h2[7] * d);
        u1.x = pk2(h2[8] * d, h2[9] * d);   u1.y = pk2(h2[10] * d, h2[11] * d);
        u1.z = pk2(h2[12] * d, h2[13] * d); u1.w = pk2(h2[14] * d, h2[15] * d);
        o[oc * 2 + 0] = u0;
        o[oc * 2 + 1] = u1;
    }
}

// ---------------- fused GCN layer (pre-scaled input h' = h*dinv) ----------------
// z[d] = dinv[d] * (sum_{s in N(d)} h'[s] + h'[d]);  y = relu(z W + b);
// store y*dinv (scale_store=1, feeds next conv) or y (scale_store=0, final layer).
DEV void add_edge_v(float* acc, uint4 u) {
    float v[8];
    unpack8(u, v);
#pragma unroll
    for (int i = 0; i < 8; i++) acc[i] += v[i];
}
__global__ __launch_bounds__(256) void k_conv_dual(const unsigned short* __restrict__ x0,
                                                   const unsigned short* __restrict__ x1,
                                                   const int* __restrict__ col0, const int* __restrict__ col1,
                                                   const int* __restrict__ r0, const int* __restrict__ r1,
                                                   const float* __restrict__ v0, const float* __restrict__ v1,
                                                   const float* __restrict__ w0, const float* __restrict__ w1,
                                                   const float* __restrict__ b0, const float* __restrict__ b1,
                                                   unsigned short* __restrict__ y0, unsigned short* __restrict__ y1,
                                                   int nblk, int scale_store) {
    int bx = blockIdx.x;
    int xcd = bx & 7;
    int g = xcd >> 2;                    // 0..3 -> graph0, 4..7 -> graph1
    int lin = (bx >> 3) * 4 + (xcd & 3); // per-graph block index
    if (lin >= nblk) return;             // block-uniform exit (barriers safe)
    const unsigned short* x = g ? x1 : x0;
    const int* col = g ? col1 : col0;
    const int* rowptr = g ? r1 : r0;
    const float* dinv = g ? v1 : v0;
    const float* w = g ? w1 : w0;
    const float* b = g ? b1 : b0;
    unsigned short* y = g ? y1 : y0;

    __shared__ int eds[ECAP];        // 8 KB staged src indices
    __shared__ float agg[32][68];    // pad 64->68: phase-2 reads conflict-free

    int t = threadIdx.x;
    int cl = t >> 3;   // local node 0..31
    int ln = t & 7;    // feature-octet lane
    int node = lin * 32 + cl;
    int fbase = ln * 8;

    int nbase = lin * 32;
    int ebase = rowptr[nbase];
    int L = rowptr[nbase + 32] - ebase;
    int Ls = (L < ECAP) ? L : ECAP;
    for (int i = t; i < Ls; i += 256) {
        eds[i] = __builtin_nontemporal_load(col + ebase + i);
    }

    float acc[8];
    float d = dinv[node];
    {
        uint4 su = *reinterpret_cast<const uint4*>(x + (size_t)node * 64 + fbase);
        float sv[8];
        unpack8(su, sv);
#pragma unroll
        for (int i = 0; i < 8; i++) acc[i] = sv[i];   // self term h'[d]
    }
    int e = rowptr[node] - ebase, e1 = rowptr[node + 1] - ebase;
    __syncthreads();

    if (e1 <= ECAP) {
        // 8 independent gathers per epoch (deg~10 -> ~2 epochs)
        for (; e + 8 <= e1; e += 8) {
            int s0 = eds[e + 0], s1 = eds[e + 1], s2 = eds[e + 2], s3 = eds[e + 3];
            int s4 = eds[e + 4], s5 = eds[e + 5], s6 = eds[e + 6], s7 = eds[e + 7];
            uint4 u0 = *reinterpret_cast<const uint4*>(x + (size_t)s0 * 64 + fbase);
            uint4 u1 = *reinterpret_cast<const uint4*>(x + (size_t)s1 * 64 + fbase);
            uint4 u2 = *reinterpret_cast<const uint4*>(x + (size_t)s2 * 64 + fbase);
            uint4 u3 = *reinterpret_cast<const uint4*>(x + (size_t)s3 * 64 + fbase);
            uint4 u4 = *reinterpret_cast<const uint4*>(x + (size_t)s4 * 64 + fbase);
            uint4 u5 = *reinterpret_cast<const uint4*>(x + (size_t)s5 * 64 + fbase);
            uint4 u6 = *reinterpret_cast<const uint4*>(x + (size_t)s6 * 64 + fbase);
            uint4 u7 = *reinterpret_cast<const uint4*>(x + (size_t)s7 * 64 + fbase);
            add_edge_v(acc, u0); add_edge_v(acc, u1); add_edge_v(acc, u2); add_edge_v(acc, u3);
            add_edge_v(acc, u4); add_edge_v(acc, u5); add_edge_v(acc, u6); add_edge_v(acc, u7);
        }
        if (e + 4 <= e1) {
            int s0 = eds[e + 0], s1 = eds[e + 1], s2 = eds[e + 2], s3 = eds[e + 3];
            uint4 u0 = *reinterpret_cast<const uint4*>(x + (size_t)s0 * 64 + fbase);
            uint4 u1 = *reinterpret_cast<const uint4*>(x + (size_t)s1 * 64 + fbase);
            uint4 u2 = *reinterpret_cast<const uint4*>(x + (size_t)s2 * 64 + fbase);
            uint4 u3 = *reinterpret_cast<const uint4*>(x + (size_t)s3 * 64 + fbase);
            add_edge_v(acc, u0); add_edge_v(acc, u1); add_edge_v(acc, u2); add_edge_v(acc, u3);
            e += 4;
        }
        if (e + 2 <= e1) {
            int s0 = eds[e + 0], s1 = eds[e + 1];
            uint4 u0 = *reinterpret_cast<const uint4*>(x + (size_t)s0 * 64 + fbase);
            uint4 u1 = *reinterpret_cast<const uint4*>(x + (size_t)s1 * 64 + fbase);
            add_edge_v(acc, u0); add_edge_v(acc, u1);
            e += 2;
        }
        if (e < e1) {
            int s0 = eds[e];
            uint4 u0 = *reinterpret_cast<const uint4*>(x + (size_t)s0 * 64 + fbase);
            add_edge_v(acc, u0);
        }
    } else {
        // overflow fallback (essentially never)
        for (; e < e1; e++) {
            int s0 = __builtin_nontemporal_load(col + ebase + e);
            uint4 u0 = *reinterpret_cast<const uint4*>(x + (size_t)s0 * 64 + fbase);
            add_edge_v(acc, u0);
        }
    }
    // z = dinv[d] * acc
#pragma unroll
    for (int i = 0; i < 8; i += 4) {
        *reinterpret_cast<float4*>(&agg[cl][fbase + i]) =
            make_float4(acc[i] * d, acc[i + 1] * d, acc[i + 2] * d, acc[i + 3] * d);
    }
    __syncthreads();

    // phase 2: out[fbase..fbase+8) = b + sum_k agg[cl][k] * W[k][fbase..]
    float out[8];
#pragma unroll
    for (int i = 0; i < 8; i++) out[i] = b[fbase + i];
#pragma unroll 4
    for (int k4 = 0; k4 < 16; k4++) {
        float4 av = *reinterpret_cast<const float4*>(&agg[cl][k4 * 4]);
        float a[4] = {av.x, av.y, av.z, av.w};
#pragma unroll
        for (int kk = 0; kk < 4; kk++) {
            const float4* wr = reinterpret_cast<const float4*>(w + (k4 * 4 + kk) * 64 + fbase);
            float4 wv0 = wr[0], wv1 = wr[1];
            out[0] = fmaf(a[kk], wv0.x, out[0]);
            out[1] = fmaf(a[kk], wv0.y, out[1]);
            out[2] = fmaf(a[kk], wv0.z, out[2]);
            out[3] = fmaf(a[kk], wv0.w, out[3]);
            out[4] = fmaf(a[kk], wv1.x, out[4]);
            out[5] = fmaf(a[kk], wv1.y, out[5]);
            out[6] = fmaf(a[kk], wv1.z, out[6]);
            out[7] = fmaf(a[kk], wv1.w, out[7]);
        }
    }
    float sc = scale_store ? d : 1.0f;
    uint4 ou;
    float r[8];
#pragma unroll
    for (int i = 0; i < 8; i++) r[i] = fmaxf(out[i], 0.0f) * sc;
    ou.x = pk2(r[0], r[1]); ou.y = pk2(r[2], r[3]); ou.z = pk2(r[4], r[5]); ou.w = pk2(r[6], r[7]);
    *reinterpret_cast<uint4*>(y + (size_t)node * 64 + fbase) = ou;
}

// ---------------- fused tail: concat-MLP + both heads ----------------
__global__ __launch_bounds__(256) void k_tail(const unsigned short* __restrict__ F,
                                              const unsigned short* __restrict__ S,
                                              const float* __restrict__ w1, const float* __restrict__ b1,
                                              const float* __restrict__ w2, const float* __restrict__ b2,
                                              const float* __restrict__ ow, const float* __restrict__ ob,
                                              const float* __restrict__ cw, const float* __restrict__ cb,
                                              float* __restrict__ out, int n) {
    int r = blockIdx.x * blockDim.x + threadIdx.x;
    if (r >= n) return;
    float h1[64];
#pragma unroll
    for (int j = 0; j < 64; j++) h1[j] = b1[j];
    const uint4* Fr = reinterpret_cast<const uint4*>(F + (size_t)r * 64);
    const uint4* Sr = reinterpret_cast<const uint4*>(S + (size_t)r * 64);
#pragma unroll 1
    for (int k0 = 0; k0 < 8; k0++) {
        uint4 u = Fr[k0];
        float v[8];
        unpack8(u, v);
        const float* wk = w1 + k0 * 8 * 64;
#pragma unroll
        for (int i = 0; i < 8; i++) {
#pragma unroll
            for (int j = 0; j < 64; j++) h1[j] = fmaf(v[i], wk[i * 64 + j], h1[j]);
        }
    }
#pragma unroll 1
    for (int k0 = 0; k0 < 8; k0++) {
        uint4 u = Sr[k0];
        float v[8];
        unpack8(u, v);
        const float* wk = w1 + (64 + k0 * 8) * 64;
#pragma unroll
        for (int i = 0; i < 8; i++) {
#pragma unroll
            for (int j = 0; j < 64; j++) h1[j] = fmaf(v[i], wk[i * 64 + j], h1[j]);
        }
    }
#pragma unroll
    for (int j = 0; j < 64; j++) h1[j] = fmaxf(h1[j], 0.0f);

    float nf[32];
#pragma unroll
    for (int j = 0; j < 32; j++) nf[j] = ob[j];
    float nt0 = cb[0], nt1 = cb[1];
#pragma unroll 1
    for (int c = 0; c < 8; c++) {  // h2 in chunks of 8
        float h2[8];
#pragma unroll
        for (int i = 0; i < 8; i++) h2[i] = b2[c * 8 + i];
#pragma unroll
        for (int k = 0; k < 64; k++) {
            const float* wr = w2 + k * 64 + c * 8;
#pragma unroll
            for (int i = 0; i < 8; i++) h2[i] = fmaf(h1[k], wr[i], h2[i]);
        }
#pragma unroll
        for (int i = 0; i < 8; i++) {
            int kk = c * 8 + i;
#pragma unroll
            for (int j = 0; j < 32; j++) nf[j] = fmaf(h2[i], ow[kk * 32 + j], nf[j]);
            nt0 = fmaf(h2[i], cw[kk * 2 + 0], nt0);
            nt1 = fmaf(h2[i], cw[kk * 2 + 1], nt1);
        }
    }
    float4* o = reinterpret_cast<float4*>(out + (size_t)r * 32);
#pragma unroll
    for (int c = 0; c < 8; c++) {
        o[c] = make_float4(nf[c * 4 + 0], nf[c * 4 + 1], nf[c * 4 + 2], nf[c * 4 + 3]);
    }
    float2* o2 = reinterpret_cast<float2*>(out + (size_t)NN * 32);
    o2[r] = make_float2(nt0, nt1);
}

extern "C" void kernel_launch(void* const* d_in, const int* in_sizes, int n_in,
                              void* d_out, int out_size, void* d_ws, size_t ws_size,
                              hipStream_t stream) {
    const int N = NN, E = EE;
    const float* front_x = (const float*)d_in[0];
    const float* side_x = (const float*)d_in[1];
    const int* fei = (const int*)d_in[2];
    const int* sei = (const int*)d_in[3];
    const float* fe_enc_w1 = (const float*)d_in[4];
    const float* fe_enc_b1 = (const float*)d_in[5];
    const float* fe_enc_w2 = (const float*)d_in[6];
    const float* fe_enc_b2 = (const float*)d_in[7];
    const float* fe_conv_w = (const float*)d_in[8];
    const float* fe_conv_b = (const float*)d_in[9];
    const float* se_enc_w1 = (const float*)d_in[10];
    const float* se_enc_b1 = (const float*)d_in[11];
    const float* se_enc_w2 = (const float*)d_in[12];
    const float* se_enc_b2 = (const float*)d_in[13];
    const float* se_conv_w = (const float*)d_in[14];
    const float* se_conv_b = (const float*)d_in[15];
    const float* fus_w1 = (const float*)d_in[16];
    const float* fus_b1 = (const float*)d_in[17];
    const float* fus_w2 = (const float*)d_in[18];
    const float* fus_b2 = (const float*)d_in[19];
    const float* out_w = (const float*)d_in[20];
    const float* out_b = (const float*)d_in[21];
    const float* cls_w = (const float*)d_in[22];
    const float* cls_b = (const float*)d_in[23];

    // workspace carve (256B aligned)
    char* ws = (char*)d_ws;
    size_t off = 0;
    auto take = [&](size_t bytes) -> char* {
        char* p = ws + off;
        off = (off + bytes + 255) & ~(size_t)255;
        return p;
    };
    int* zb = (int*)take((size_t)2 * N * 4);  // cnt0,cnt1 (zeroed)
    int* cnt0 = zb;
    int* cnt1 = zb + N;
    int* pos0 = (int*)take((size_t)E * 4);
    int* pos1 = (int*)take((size_t)E * 4);
    int* rp0 = (int*)take((size_t)(N + 1) * 4);
    int* rp1 = (int*)take((size_t)(N + 1) * 4);
    float* dv0 = (float*)take((size_t)N * 4);
    float* dv1 = (float*)take((size_t)N * 4);
    int* part0 = (int*)take(256 * 4);
    int* part1 = (int*)take(256 * 4);
    int* col0 = (int*)take((size_t)E * 4);
    int* col1 = (int*)take((size_t)E * 4);
    unsigned short* P0 = (unsigned short*)take((size_t)N * 64 * 2);
    unsigned short* P1 = (unsigned short*)take((size_t)N * 64 * 2);
    unsigned short* Q0 = (unsigned short*)take((size_t)N * 64 * 2);
    unsigned short* Q1 = (unsigned short*)take((size_t)N * 64 * 2);

    const int NB_ROW = (N + 255) / 256;
    const int NB_E = (E + 255) / 256;
    const int NB_C = N / 32;                       // 3125 blocks per graph
    const int GX_C = ((2 * NB_C + 7) / 8) * 8;     // XCD-aligned grid for conv
    const int SB = (N + 1023) / 1024;

    // ---- CSR build for both graphs ----
    hipMemsetAsync(zb, 0, (size_t)2 * N * 4, stream);
    k_count_dual<<<dim3(NB_E, 2), 256, 0, stream>>>(fei + E, sei + E, cnt0, cnt1, pos0, pos1, E);
    k_scan_partial_dual<<<dim3(SB, 2), 256, 0, stream>>>(cnt0, cnt1, part0, part1, dv0, dv1, N);
    k_scan_single_dual<<<dim3(1, 2), 256, 0, stream>>>(part0, part1, SB);
    k_scan_write_dual<<<dim3(SB, 2), 256, 0, stream>>>(cnt0, cnt1, part0, part1, rp0, rp1, N, E);
    k_fill_dual<<<dim3(NB_E, 2), 256, 0, stream>>>(fei, sei, pos0, pos1, rp0, rp1, col0, col1, E);

    // ---- encoders (dual, fused 2-layer MLP; output pre-scaled by dinv) ----
    k_enc_dual<<<dim3(NB_ROW, 2), 256, 0, stream>>>(front_x, side_x, fe_enc_w1, se_enc_w1,
                                                    fe_enc_b1, se_enc_b1, fe_enc_w2, se_enc_w2,
                                                    fe_enc_b2, se_enc_b2, dv0, dv1, Q0, Q1, N);
    // ---- 3 fused conv layers (XCD-partitioned dual, LDS-staged col):  Q->P->Q->P ----
    k_conv_dual<<<GX_C, 256, 0, stream>>>(Q0, Q1, col0, col1, rp0, rp1, dv0, dv1,
                                          fe_conv_w + 0 * 4096, se_conv_w + 0 * 4096,
                                          fe_conv_b + 0 * 64, se_conv_b + 0 * 64, P0, P1, NB_C, 1);
    k_conv_dual<<<GX_C, 256, 0, stream>>>(P0, P1, col0, col1, rp0, rp1, dv0, dv1,
                                          fe_conv_w + 1 * 4096, se_conv_w + 1 * 4096,
                                          fe_conv_b + 1 * 64, se_conv_b + 1 * 64, Q0, Q1, NB_C, 1);
    k_conv_dual<<<GX_C, 256, 0, stream>>>(Q0, Q1, col0, col1, rp0, rp1, dv0, dv1,
                                          fe_conv_w + 2 * 4096, se_conv_w + 2 * 4096,
                                          fe_conv_b + 2 * 64, se_conv_b + 2 * 64, P0, P1, NB_C, 0);

    // ---- fused fusion-MLP + heads ----
    k_tail<<<NB_ROW, 256, 0, stream>>>(P0, P1, fus_w1, fus_b1, fus_w2, fus_b2,
                                       out_w, out_b, cls_w, cls_b, (float*)d_out, N);
}

// Round 12
// 726.207 us; speedup vs baseline: 3.3076x; 1.0073x over previous
//
#include <hip/hip_runtime.h>

#define DEV __device__ __forceinline__

static const int NN = 100000;
static const int EE = 1000000;
static const int ECAP = 1024;   // LDS-staged edges per block (32 nodes, avg ~320)

typedef unsigned int uv4 __attribute__((ext_vector_type(4)));

DEV float bf2f(unsigned int h) {
    unsigned int u = h << 16;
    float f;
    __builtin_memcpy(&f, &u, 4);
    return f;
}
DEV unsigned short f2bf(float f) {  // round-to-nearest-even
    unsigned int u;
    __builtin_memcpy(&u, &f, 4);
    u = u + 0x7FFFu + ((u >> 16) & 1u);
    return (unsigned short)(u >> 16);
}
DEV unsigned int pk2(float a, float b) {
    return (unsigned int)f2bf(a) | ((unsigned int)f2bf(b) << 16);
}
DEV void unpack8(uint4 u, float* v) {
    v[0] = bf2f(u.x & 0xffffu); v[1] = bf2f(u.x >> 16);
    v[2] = bf2f(u.y & 0xffffu); v[3] = bf2f(u.y >> 16);
    v[4] = bf2f(u.z & 0xffffu); v[5] = bf2f(u.z >> 16);
    v[6] = bf2f(u.w & 0xffffu); v[7] = bf2f(u.w >> 16);
}

// ---------------- CSR build (dual-graph via blockIdx.y) ----------------
__global__ __launch_bounds__(256) void k_count_dual(const int* __restrict__ d0, const int* __restrict__ d1,
                                                    int* __restrict__ c0, int* __restrict__ c1,
                                                    int* __restrict__ p0, int* __restrict__ p1, int e) {
    int g = blockIdx.y;
    const int* dst = g ? d1 : d0;
    int* cnt = g ? c1 : c0;
    int* pos = g ? p1 : p0;
    int i = blockIdx.x * blockDim.x + threadIdx.x;
    if (i < e) pos[i] = atomicAdd(&cnt[dst[i]], 1);
}
__global__ __launch_bounds__(256) void k_scan_partial_dual(const int* __restrict__ c0, const int* __restrict__ c1,
                                                           int* __restrict__ p0, int* __restrict__ p1,
                                                           float* __restrict__ v0, float* __restrict__ v1, int n) {
    int g = blockIdx.y;
    const int* cnt = g ? c1 : c0;
    int* partial = g ? p1 : p0;
    float* dinv = g ? v1 : v0;
    __shared__ int lds[256];
    int base = blockIdx.x * 1024;
    int t = threadIdx.x;
    int s = 0;
#pragma unroll
    for (int i = 0; i < 4; i++) {
        int idx = base + t * 4 + i;
        int c = (idx < n) ? cnt[idx] : 0;
        if (idx < n) dinv[idx] = rsqrtf((float)c + 1.0f);
        s += c;
    }
    lds[t] = s;
    __syncthreads();
    for (int off = 128; off > 0; off >>= 1) {
        if (t < off) lds[t] += lds[t + off];
        __syncthreads();
    }
    if (t == 0) partial[blockIdx.x] = lds[0];
}
// scan_write with INLINE top-level scan of partials (scan_single eliminated)
__global__ __launch_bounds__(256) void k_scan_write_dual(const int* __restrict__ c0, const int* __restrict__ c1,
                                                         const int* __restrict__ p0, const int* __restrict__ p1,
                                                         int* __restrict__ r0, int* __restrict__ r1,
                                                         int n, int total, int B) {
    int g = blockIdx.y;
    const int* cnt = g ? c1 : c0;
    const int* partial = g ? p1 : p0;
    int* rowptr = g ? r1 : r0;
    __shared__ int val[256];
    __shared__ int top[256];
    __shared__ int lds[256];
    __shared__ int base_s;
    int t = threadIdx.x;
    // top-level exclusive scan of partials (each block redundantly; B<=256)
    int pv = (t < B) ? partial[t] : 0;
    val[t] = pv;
    top[t] = pv;
    __syncthreads();
    for (int off = 1; off < 256; off <<= 1) {
        int x = (t >= off) ? top[t - off] : 0;
        __syncthreads();
        top[t] += x;
        __syncthreads();
    }
    if (t == 0) base_s = top[blockIdx.x] - val[blockIdx.x];  // exclusive prefix @ this block
    __syncthreads();
    // local scan over this block's 1024 cnt entries
    int base = blockIdx.x * 1024;
    int v[4];
    int s = 0;
#pragma unroll
    for (int i = 0; i < 4; i++) {
        int idx = base + t * 4 + i;
        v[i] = (idx < n) ? cnt[idx] : 0;
        s += v[i];
    }
    lds[t] = s;
    __syncthreads();
    int mine = s;
    for (int off = 1; off < 256; off <<= 1) {
        int x = (t >= off) ? lds[t - off] : 0;
        __syncthreads();
        lds[t] += x;
        __syncthreads();
    }
    int run = lds[t] - mine + base_s;
#pragma unroll
    for (int i = 0; i < 4; i++) {
        int idx = base + t * 4 + i;
        if (idx < n) rowptr[idx] = run;
        run += v[i];
    }
    if (blockIdx.x == 0 && t == 0) rowptr[n] = total;
}

// ---------------- merged fill + encoder (independent work, one dispatch) ----------------
// blocks [0, 2*nbe): fill  —  col[rowptr[d]+pos[i]] = src
// blocks [2*nbe, 2*nbe+2*nbr): enc — (relu(x@w1+b1)@w2+b2)*dinv -> bf16 (register-bounded)
__global__ __launch_bounds__(256, 4) void k_fillenc_dual(
    const int* __restrict__ s0, const int* __restrict__ s1,
    const int* __restrict__ q0, const int* __restrict__ q1,
    const int* __restrict__ r0, const int* __restrict__ r1,
    int* __restrict__ col0, int* __restrict__ col1, int e,
    const float* __restrict__ x0, const float* __restrict__ x1,
    const float* __restrict__ w1a, const float* __restrict__ w1b,
    const float* __restrict__ b1a, const float* __restrict__ b1b,
    const float* __restrict__ w2a, const float* __restrict__ w2b,
    const float* __restrict__ b2a, const float* __restrict__ b2b,
    const float* __restrict__ v0, const float* __restrict__ v1,
    unsigned short* __restrict__ y0, unsigned short* __restrict__ y1,
    int n, int nbe, int nbr) {
    int bx = blockIdx.x;
    int t = threadIdx.x;
    if (bx < 2 * nbe) {
        // ---- fill path ----
        int g = (bx >= nbe) ? 1 : 0;
        const int* src = g ? s1 : s0;
        const int* dstv = src + e;
        const int* pos = g ? q1 : q0;
        const int* rowptr = g ? r1 : r0;
        int* col = g ? col1 : col0;
        int i = (bx - g * nbe) * 256 + t;
        if (i >= e) return;
        int s = src[i], d = dstv[i];
        int idx = rowptr[d] + pos[i];
        __builtin_nontemporal_store(s, col + idx);
        return;
    }
    // ---- enc path ----
    int bx2 = bx - 2 * nbe;
    int g = (bx2 >= nbr) ? 1 : 0;
    const float* x = g ? x1 : x0;
    const float* w1 = g ? w1b : w1a;
    const float* b1 = g ? b1b : b1a;
    const float* w2 = g ? w2b : w2a;
    const float* b2 = g ? b2b : b2a;
    const float* dinv = g ? v1 : v0;
    unsigned short* out = g ? y1 : y0;
    int r = (bx2 - g * nbr) * 256 + t;
    if (r >= n) return;
    float4 xv = reinterpret_cast<const float4*>(x)[r];
    float xk[4] = {xv.x, xv.y, xv.z, xv.w};
    float d = dinv[r];
    uint4* o = reinterpret_cast<uint4*>(out + (size_t)r * 64);
#pragma unroll 1
    for (int oc = 0; oc < 4; oc++) {          // 16 output columns per chunk
        float h2[16];
#pragma unroll
        for (int j = 0; j < 16; j++) h2[j] = b2[oc * 16 + j];
#pragma unroll 1
        for (int c = 0; c < 8; c++) {         // h1 in chunks of 8 (recomputed)
            float h[8];
#pragma unroll
            for (int i = 0; i < 8; i++) h[i] = b1[c * 8 + i];
#pragma unroll
            for (int k = 0; k < 4; k++) {
#pragma unroll
                for (int i = 0; i < 8; i++) h[i] = fmaf(xk[k], w1[k * 64 + c * 8 + i], h[i]);
            }
#pragma unroll
            for (int i = 0; i < 8; i++) h[i] = fmaxf(h[i], 0.0f);
#pragma unroll
            for (int i = 0; i < 8; i++) {
                const float* wr = w2 + (c * 8 + i) * 64 + oc * 16;
#pragma unroll
                for (int j = 0; j < 16; j++) h2[j] = fmaf(h[i], wr[j], h2[j]);
            }
        }
        uint4 u0, u1;
        u0.x = pk2(h2[0] * d, h2[1] * d);   u0.y = pk2(h2[2] * d, h2[3] * d);
        u0.z = pk2(h2[4] * d, h2[5] * d);   u0.w = pk2(h2[6] * d, h2[7] * d);
        u1.x = pk2(h2[8] * d, h2[9] * d);   u1.y = pk2(h2[10] * d, h2[11] * d);
        u1.z = pk2(h2[12] * d, h2[13] * d); u1.w = pk2(h2[14] * d, h2[15] * d);
        o[oc * 2 + 0] = u0;
        o[oc * 2 + 1] = u1;
    }
}

// ---------------- fused GCN layer (pre-scaled input h' = h*dinv) ----------------
// z[d] = dinv[d] * (sum_{s in N(d)} h'[s] + h'[d]);  y = relu(z W + b);
// store y*dinv (scale_store=1, feeds next conv) or y (scale_store=0, final layer).
DEV void add_edge_v(float* acc, uint4 u) {
    float v[8];
    unpack8(u, v);
#pragma unroll
    for (int i = 0; i < 8; i++) acc[i] += v[i];
}
__global__ __launch_bounds__(256) void k_conv_dual(const unsigned short* __restrict__ x0,
                                                   const unsigned short* __restrict__ x1,
                                                   const int* __restrict__ col0, const int* __restrict__ col1,
                                                   const int* __restrict__ r0, const int* __restrict__ r1,
                                                   const float* __restrict__ v0, const float* __restrict__ v1,
                                                   const float* __restrict__ w0, const float* __restrict__ w1,
                                                   const float* __restrict__ b0, const float* __restrict__ b1,
                                                   unsigned short* __restrict__ y0, unsigned short* __restrict__ y1,
                                                   int nblk, int scale_store) {
    int bx = blockIdx.x;
    int xcd = bx & 7;
    int g = xcd >> 2;                    // 0..3 -> graph0, 4..7 -> graph1
    int lin = (bx >> 3) * 4 + (xcd & 3); // per-graph block index
    if (lin >= nblk) return;             // block-uniform exit (barriers safe)
    const unsigned short* x = g ? x1 : x0;
    const int* col = g ? col1 : col0;
    const int* rowptr = g ? r1 : r0;
    const float* dinv = g ? v1 : v0;
    const float* w = g ? w1 : w0;
    const float* b = g ? b1 : b0;
    unsigned short* y = g ? y1 : y0;

    __shared__ int eds[ECAP];        // 4 KB staged src indices
    __shared__ float agg[32][68];    // pad 64->68: phase-2 reads conflict-free

    int t = threadIdx.x;
    int cl = t >> 3;   // local node 0..31
    int ln = t & 7;    // feature-octet lane
    int node = lin * 32 + cl;
    int fbase = ln * 8;

    int nbase = lin * 32;
    int ebase = rowptr[nbase];
    int L = rowptr[nbase + 32] - ebase;
    int Ls = (L < ECAP) ? L : ECAP;
    for (int i = t; i < Ls; i += 256) {
        eds[i] = __builtin_nontemporal_load(col + ebase + i);
    }

    float acc[8];
    float d = dinv[node];
    {
        uint4 su = *reinterpret_cast<const uint4*>(x + (size_t)node * 64 + fbase);
        float sv[8];
        unpack8(su, sv);
#pragma unroll
        for (int i = 0; i < 8; i++) acc[i] = sv[i];   // self term h'[d]
    }
    int e = rowptr[node] - ebase, e1 = rowptr[node + 1] - ebase;
    __syncthreads();

    if (e1 <= ECAP) {
        // 8 independent gathers per epoch (deg~10 -> ~2 epochs)
        for (; e + 8 <= e1; e += 8) {
            int s0 = eds[e + 0], s1 = eds[e + 1], s2 = eds[e + 2], s3 = eds[e + 3];
            int s4 = eds[e + 4], s5 = eds[e + 5], s6 = eds[e + 6], s7 = eds[e + 7];
            uint4 u0 = *reinterpret_cast<const uint4*>(x + (size_t)s0 * 64 + fbase);
            uint4 u1 = *reinterpret_cast<const uint4*>(x + (size_t)s1 * 64 + fbase);
            uint4 u2 = *reinterpret_cast<const uint4*>(x + (size_t)s2 * 64 + fbase);
            uint4 u3 = *reinterpret_cast<const uint4*>(x + (size_t)s3 * 64 + fbase);
            uint4 u4 = *reinterpret_cast<const uint4*>(x + (size_t)s4 * 64 + fbase);
            uint4 u5 = *reinterpret_cast<const uint4*>(x + (size_t)s5 * 64 + fbase);
            uint4 u6 = *reinterpret_cast<const uint4*>(x + (size_t)s6 * 64 + fbase);
            uint4 u7 = *reinterpret_cast<const uint4*>(x + (size_t)s7 * 64 + fbase);
            add_edge_v(acc, u0); add_edge_v(acc, u1); add_edge_v(acc, u2); add_edge_v(acc, u3);
            add_edge_v(acc, u4); add_edge_v(acc, u5); add_edge_v(acc, u6); add_edge_v(acc, u7);
        }
        if (e + 4 <= e1) {
            int s0 = eds[e + 0], s1 = eds[e + 1], s2 = eds[e + 2], s3 = eds[e + 3];
            uint4 u0 = *reinterpret_cast<const uint4*>(x + (size_t)s0 * 64 + fbase);
            uint4 u1 = *reinterpret_cast<const uint4*>(x + (size_t)s1 * 64 + fbase);
            uint4 u2 = *reinterpret_cast<const uint4*>(x + (size_t)s2 * 64 + fbase);
            uint4 u3 = *reinterpret_cast<const uint4*>(x + (size_t)s3 * 64 + fbase);
            add_edge_v(acc, u0); add_edge_v(acc, u1); add_edge_v(acc, u2); add_edge_v(acc, u3);
            e += 4;
        }
        if (e + 2 <= e1) {
            int s0 = eds[e + 0], s1 = eds[e + 1];
            uint4 u0 = *reinterpret_cast<const uint4*>(x + (size_t)s0 * 64 + fbase);
            uint4 u1 = *reinterpret_cast<const uint4*>(x + (size_t)s1 * 64 + fbase);
            add_edge_v(acc, u0); add_edge_v(acc, u1);
            e += 2;
        }
        if (e < e1) {
            int s0 = eds[e];
            uint4 u0 = *reinterpret_cast<const uint4*>(x + (size_t)s0 * 64 + fbase);
            add_edge_v(acc, u0);
        }
    } else {
        // overflow fallback (essentially never)
        for (; e < e1; e++) {
            int s0 = __builtin_nontemporal_load(col + ebase + e);
            uint4 u0 = *reinterpret_cast<const uint4*>(x + (size_t)s0 * 64 + fbase);
            add_edge_v(acc, u0);
        }
    }
    // z = dinv[d] * acc
#pragma unroll
    for (int i = 0; i < 8; i += 4) {
        *reinterpret_cast<float4*>(&agg[cl][fbase + i]) =
            make_float4(acc[i] * d, acc[i + 1] * d, acc[i + 2] * d, acc[i + 3] * d);
    }
    __syncthreads();

    // phase 2: out[fbase..fbase+8) = b + sum_k agg[cl][k] * W[k][fbase..]
    float out[8];
#pragma unroll
    for (int i = 0; i < 8; i++) out[i] = b[fbase + i];
#pragma unroll 4
    for (int k4 = 0; k4 < 16; k4++) {
        float4 av = *reinterpret_cast<const float4*>(&agg[cl][k4 * 4]);
        float a[4] = {av.x, av.y, av.z, av.w};
#pragma unroll
        for (int kk = 0; kk < 4; kk++) {
            const float4* wr = reinterpret_cast<const float4*>(w + (k4 * 4 + kk) * 64 + fbase);
            float4 wv0 = wr[0], wv1 = wr[1];
            out[0] = fmaf(a[kk], wv0.x, out[0]);
            out[1] = fmaf(a[kk], wv0.y, out[1]);
            out[2] = fmaf(a[kk], wv0.z, out[2]);
            out[3] = fmaf(a[kk], wv0.w, out[3]);
            out[4] = fmaf(a[kk], wv1.x, out[4]);
            out[5] = fmaf(a[kk], wv1.y, out[5]);
            out[6] = fmaf(a[kk], wv1.z, out[6]);
            out[7] = fmaf(a[kk], wv1.w, out[7]);
        }
    }
    float sc = scale_store ? d : 1.0f;
    uint4 ou;
    float r[8];
#pragma unroll
    for (int i = 0; i < 8; i++) r[i] = fmaxf(out[i], 0.0f) * sc;
    ou.x = pk2(r[0], r[1]); ou.y = pk2(r[2], r[3]); ou.z = pk2(r[4], r[5]); ou.w = pk2(r[6], r[7]);
    *reinterpret_cast<uint4*>(y + (size_t)node * 64 + fbase) = ou;
}

// ---------------- fused tail: concat-MLP + both heads ----------------
__global__ __launch_bounds__(256) void k_tail(const unsigned short* __restrict__ F,
                                              const unsigned short* __restrict__ S,
                                              const float* __restrict__ w1, const float* __restrict__ b1,
                                              const float* __restrict__ w2, const float* __restrict__ b2,
                                              const float* __restrict__ ow, const float* __restrict__ ob,
                                              const float* __restrict__ cw, const float* __restrict__ cb,
                                              float* __restrict__ out, int n) {
    int r = blockIdx.x * blockDim.x + threadIdx.x;
    if (r >= n) return;
    float h1[64];
#pragma unroll
    for (int j = 0; j < 64; j++) h1[j] = b1[j];
    const uint4* Fr = reinterpret_cast<const uint4*>(F + (size_t)r * 64);
    const uint4* Sr = reinterpret_cast<const uint4*>(S + (size_t)r * 64);
#pragma unroll 1
    for (int k0 = 0; k0 < 8; k0++) {
        uint4 u = Fr[k0];
        float v[8];
        unpack8(u, v);
        const float* wk = w1 + k0 * 8 * 64;
#pragma unroll
        for (int i = 0; i < 8; i++) {
#pragma unroll
            for (int j = 0; j < 64; j++) h1[j] = fmaf(v[i], wk[i * 64 + j], h1[j]);
        }
    }
#pragma unroll 1
    for (int k0 = 0; k0 < 8; k0++) {
        uint4 u = Sr[k0];
        float v[8];
        unpack8(u, v);
        const float* wk = w1 + (64 + k0 * 8) * 64;
#pragma unroll
        for (int i = 0; i < 8; i++) {
#pragma unroll
            for (int j = 0; j < 64; j++) h1[j] = fmaf(v[i], wk[i * 64 + j], h1[j]);
        }
    }
#pragma unroll
    for (int j = 0; j < 64; j++) h1[j] = fmaxf(h1[j], 0.0f);

    float nf[32];
#pragma unroll
    for (int j = 0; j < 32; j++) nf[j] = ob[j];
    float nt0 = cb[0], nt1 = cb[1];
#pragma unroll 1
    for (int c = 0; c < 8; c++) {  // h2 in chunks of 8
        float h2[8];
#pragma unroll
        for (int i = 0; i < 8; i++) h2[i] = b2[c * 8 + i];
#pragma unroll
        for (int k = 0; k < 64; k++) {
            const float* wr = w2 + k * 64 + c * 8;
#pragma unroll
            for (int i = 0; i < 8; i++) h2[i] = fmaf(h1[k], wr[i], h2[i]);
        }
#pragma unroll
        for (int i = 0; i < 8; i++) {
            int kk = c * 8 + i;
#pragma unroll
            for (int j = 0; j < 32; j++) nf[j] = fmaf(h2[i], ow[kk * 32 + j], nf[j]);
            nt0 = fmaf(h2[i], cw[kk * 2 + 0], nt0);
            nt1 = fmaf(h2[i], cw[kk * 2 + 1], nt1);
        }
    }
    float4* o = reinterpret_cast<float4*>(out + (size_t)r * 32);
#pragma unroll
    for (int c = 0; c < 8; c++) {
        o[c] = make_float4(nf[c * 4 + 0], nf[c * 4 + 1], nf[c * 4 + 2], nf[c * 4 + 3]);
    }
    float2* o2 = reinterpret_cast<float2*>(out + (size_t)NN * 32);
    o2[r] = make_float2(nt0, nt1);
}

extern "C" void kernel_launch(void* const* d_in, const int* in_sizes, int n_in,
                              void* d_out, int out_size, void* d_ws, size_t ws_size,
                              hipStream_t stream) {
    const int N = NN, E = EE;
    const float* front_x = (const float*)d_in[0];
    const float* side_x = (const float*)d_in[1];
    const int* fei = (const int*)d_in[2];
    const int* sei = (const int*)d_in[3];
    const float* fe_enc_w1 = (const float*)d_in[4];
    const float* fe_enc_b1 = (const float*)d_in[5];
    const float* fe_enc_w2 = (const float*)d_in[6];
    const float* fe_enc_b2 = (const float*)d_in[7];
    const float* fe_conv_w = (const float*)d_in[8];
    const float* fe_conv_b = (const float*)d_in[9];
    const float* se_enc_w1 = (const float*)d_in[10];
    const float* se_enc_b1 = (const float*)d_in[11];
    const float* se_enc_w2 = (const float*)d_in[12];
    const float* se_enc_b2 = (const float*)d_in[13];
    const float* se_conv_w = (const float*)d_in[14];
    const float* se_conv_b = (const float*)d_in[15];
    const float* fus_w1 = (const float*)d_in[16];
    const float* fus_b1 = (const float*)d_in[17];
    const float* fus_w2 = (const float*)d_in[18];
    const float* fus_b2 = (const float*)d_in[19];
    const float* out_w = (const float*)d_in[20];
    const float* out_b = (const float*)d_in[21];
    const float* cls_w = (const float*)d_in[22];
    const float* cls_b = (const float*)d_in[23];

    // workspace carve (256B aligned)
    char* ws = (char*)d_ws;
    size_t off = 0;
    auto take = [&](size_t bytes) -> char* {
        char* p = ws + off;
        off = (off + bytes + 255) & ~(size_t)255;
        return p;
    };
    int* zb = (int*)take((size_t)2 * N * 4);  // cnt0,cnt1 (zeroed)
    int* cnt0 = zb;
    int* cnt1 = zb + N;
    int* pos0 = (int*)take((size_t)E * 4);
    int* pos1 = (int*)take((size_t)E * 4);
    int* rp0 = (int*)take((size_t)(N + 1) * 4);
    int* rp1 = (int*)take((size_t)(N + 1) * 4);
    float* dv0 = (float*)take((size_t)N * 4);
    float* dv1 = (float*)take((size_t)N * 4);
    int* part0 = (int*)take(256 * 4);
    int* part1 = (int*)take(256 * 4);
    int* col0 = (int*)take((size_t)E * 4);
    int* col1 = (int*)take((size_t)E * 4);
    unsigned short* P0 = (unsigned short*)take((size_t)N * 64 * 2);
    unsigned short* P1 = (unsigned short*)take((size_t)N * 64 * 2);
    unsigned short* Q0 = (unsigned short*)take((size_t)N * 64 * 2);
    unsigned short* Q1 = (unsigned short*)take((size_t)N * 64 * 2);

    const int NB_ROW = (N + 255) / 256;
    const int NB_E = (E + 255) / 256;
    const int NB_C = N / 32;                       // 3125 blocks per graph
    const int GX_C = ((2 * NB_C + 7) / 8) * 8;     // XCD-aligned grid for conv
    const int SB = (N + 1023) / 1024;              // 98 partial blocks

    // ---- CSR build for both graphs ----
    hipMemsetAsync(zb, 0, (size_t)2 * N * 4, stream);
    k_count_dual<<<dim3(NB_E, 2), 256, 0, stream>>>(fei + E, sei + E, cnt0, cnt1, pos0, pos1, E);
    k_scan_partial_dual<<<dim3(SB, 2), 256, 0, stream>>>(cnt0, cnt1, part0, part1, dv0, dv1, N);
    k_scan_write_dual<<<dim3(SB, 2), 256, 0, stream>>>(cnt0, cnt1, part0, part1, rp0, rp1, N, E, SB);

    // ---- merged fill + encoders (one dispatch; independent work) ----
    k_fillenc_dual<<<2 * NB_E + 2 * NB_ROW, 256, 0, stream>>>(
        fei, sei, pos0, pos1, rp0, rp1, col0, col1, E,
        front_x, side_x, fe_enc_w1, se_enc_w1, fe_enc_b1, se_enc_b1,
        fe_enc_w2, se_enc_w2, fe_enc_b2, se_enc_b2, dv0, dv1, Q0, Q1,
        N, NB_E, NB_ROW);

    // ---- 3 fused conv layers (XCD-partitioned dual, LDS-staged col):  Q->P->Q->P ----
    k_conv_dual<<<GX_C, 256, 0, stream>>>(Q0, Q1, col0, col1, rp0, rp1, dv0, dv1,
                                          fe_conv_w + 0 * 4096, se_conv_w + 0 * 4096,
                                          fe_conv_b + 0 * 64, se_conv_b + 0 * 64, P0, P1, NB_C, 1);
    k_conv_dual<<<GX_C, 256, 0, stream>>>(P0, P1, col0, col1, rp0, rp1, dv0, dv1,
                                          fe_conv_w + 1 * 4096, se_conv_w + 1 * 4096,
                                          fe_conv_b + 1 * 64, se_conv_b + 1 * 64, Q0, Q1, NB_C, 1);
    k_conv_dual<<<GX_C, 256, 0, stream>>>(Q0, Q1, col0, col1, rp0, rp1, dv0, dv1,
                                          fe_conv_w + 2 * 4096, se_conv_w + 2 * 4096,
                                          fe_conv_b + 2 * 64, se_conv_b + 2 * 64, P0, P1, NB_C, 0);

    // ---- fused fusion-MLP + heads ----
    k_tail<<<NB_ROW, 256, 0, stream>>>(P0, P1, fus_w1, fus_b1, fus_w2, fus_b2,
                                       out_w, out_b, cls_w, cls_b, (float*)d_out, N);
}